// Round 3
// baseline (816.912 us; speedup 1.0000x reference)
//
#include <hip/hip_runtime.h>
#include <hip/hip_bf16.h>
#include <math.h>

#define IN_DIM 256
#define OUT_DIM 64

__device__ __forceinline__ float edge_score(float x) {
    float e = x > 0.0f ? x : 0.01f * x;   // leaky_relu, slope 0.01
    if (e == 0.0f) e = -1000.0f;          // where(e==0, -1000, e)
    return e;
}

// z = h @ W_fc (W_fc in LDS, h rows via scalar loads), s[row] = dot(z[row], W_attn[:64])
// 1024-thread blocks: 64KB LDS -> 2 blocks/CU -> 32 waves/CU (8/SIMD).
__global__ __launch_bounds__(1024, 8) void gemm_s_kernel(
    const float* __restrict__ h, const float* __restrict__ Wfc,
    const float* __restrict__ Wattn, __hip_bfloat16* __restrict__ z,
    float* __restrict__ s, int n_rows)
{
    __shared__ float Wlds[IN_DIM * OUT_DIM];   // 64 KB
    const int tid = threadIdx.x;
    {
        const float4* W4 = (const float4*)Wfc;
        float4* L4 = (float4*)Wlds;
        #pragma unroll
        for (int i = 0; i < 4; ++i)
            L4[tid + i * 1024] = W4[tid + i * 1024];
    }
    __syncthreads();

    const int lane = tid & 63;
    const int wv = tid >> 6;
    const float a = Wattn[lane];
    const int row0 = blockIdx.x * 128 + wv * 8;

    // wave-uniform clamped row bases -> compiler emits s_load for h
    size_t base[8];
    #pragma unroll
    for (int r = 0; r < 8; ++r)
        base[r] = (size_t)min(row0 + r, n_rows - 1) * (IN_DIM / 4);

    const float4* h4 = (const float4*)h;
    float acc[8];
    #pragma unroll
    for (int r = 0; r < 8; ++r) acc[r] = 0.0f;

    #pragma unroll 2
    for (int k4 = 0; k4 < IN_DIM / 4; ++k4) {
        float4 hv[8];
        #pragma unroll
        for (int r = 0; r < 8; ++r) hv[r] = h4[base[r] + k4];
        const float w0 = Wlds[(k4 * 4 + 0) * OUT_DIM + lane];
        const float w1 = Wlds[(k4 * 4 + 1) * OUT_DIM + lane];
        const float w2 = Wlds[(k4 * 4 + 2) * OUT_DIM + lane];
        const float w3 = Wlds[(k4 * 4 + 3) * OUT_DIM + lane];
        #pragma unroll
        for (int r = 0; r < 8; ++r)
            acc[r] = fmaf(hv[r].w, w3, fmaf(hv[r].z, w2,
                     fmaf(hv[r].y, w1, fmaf(hv[r].x, w0, acc[r]))));
    }

    #pragma unroll
    for (int r = 0; r < 8; ++r) {
        const int row = row0 + r;
        if (row < n_rows)
            z[(size_t)row * OUT_DIM + lane] = __float2bfloat16(acc[r]);
        float p = acc[r] * a;
        #pragma unroll
        for (int o = 32; o > 0; o >>= 1) p += __shfl_xor(p, o);
        if (lane == 0 && row < n_rows) s[row] = p;
    }
}

// count[dst]++
__global__ __launch_bounds__(256) void hist_kernel(
    const int* __restrict__ dst, int* __restrict__ cnt, int n_edges)
{
    int i = blockIdx.x * blockDim.x + threadIdx.x;
    int stride = gridDim.x * blockDim.x;
    for (; i < n_edges; i += stride) atomicAdd(cnt + dst[i], 1);
}

// single-block exclusive scan of cnt[0..n) -> off[] and woff[]; off[n]=total
__global__ __launch_bounds__(1024) void scan_kernel(
    const int* __restrict__ cnt, int* __restrict__ off, int* __restrict__ woff, int n)
{
    __shared__ int ssum[1024];
    const int t = threadIdx.x;
    const int chunk = (n + 1023) >> 10;
    const int b = t * chunk;
    const int e = min(b + chunk, n);
    int local = 0;
    for (int i = b; i < e; ++i) local += cnt[i];
    ssum[t] = local;
    __syncthreads();
    for (int d = 1; d < 1024; d <<= 1) {
        int v = (t >= d) ? ssum[t - d] : 0;
        __syncthreads();
        ssum[t] += v;
        __syncthreads();
    }
    int run = ssum[t] - local;
    for (int i = b; i < e; ++i) {
        off[i] = run; woff[i] = run;
        run += cnt[i];
    }
    if (t == 1023) off[n] = ssum[1023];
}

// bin edges by dst; also precompute per-edge score e
__global__ __launch_bounds__(256) void bin_kernel(
    const int* __restrict__ src, const int* __restrict__ dst,
    const float* __restrict__ s, int* __restrict__ woff,
    int* __restrict__ sorted_src, float* __restrict__ sorted_e, int n_edges)
{
    int i = blockIdx.x * blockDim.x + threadIdx.x;
    int stride = gridDim.x * blockDim.x;
    for (; i < n_edges; i += stride) {
        int sr = src[i];
        float e = edge_score(s[sr]);
        int pos = atomicAdd(woff + dst[i], 1);
        sorted_src[pos] = sr;
        sorted_e[pos] = e;
    }
}

// one wave per pnode: softmax over its contiguous edge segment + weighted z-sum
__global__ __launch_bounds__(256) void segment_kernel(
    const int* __restrict__ off, const int* __restrict__ sorted_src,
    const float* __restrict__ sorted_e, const __hip_bfloat16* __restrict__ z,
    float* __restrict__ out, int n_pnodes)
{
    const int p = blockIdx.x * 4 + (threadIdx.x >> 6);
    if (p >= n_pnodes) return;
    const int lane = threadIdx.x & 63;
    const int beg = off[p];
    const int end = off[p + 1];

    if (beg == end) {
        out[(size_t)p * OUT_DIM + lane] = 0.0f;
        return;
    }

    float m = -INFINITY;
    for (int j = beg + lane; j < end; j += 64) m = fmaxf(m, sorted_e[j]);
    #pragma unroll
    for (int o = 32; o > 0; o >>= 1) m = fmaxf(m, __shfl_xor(m, o));

    float acc = 0.0f, dsum = 0.0f;
    for (int c = beg; c < end; c += 64) {
        const int j = c + lane;
        const bool v = j < end;
        float w = 0.0f;
        int sr = 0;
        if (v) {
            w = __expf(sorted_e[j] - m);
            sr = sorted_src[j];
        }
        dsum += w;
        const int cn = min(64, end - c);
        for (int t = 0; t < cn; ++t) {
            float wt = __shfl(w, t);
            int st = __shfl(sr, t);
            acc = fmaf(wt, __bfloat162float(z[(size_t)st * OUT_DIM + lane]), acc);
        }
    }
    #pragma unroll
    for (int o = 32; o > 0; o >>= 1) dsum += __shfl_xor(dsum, o);
    out[(size_t)p * OUT_DIM + lane] = acc / fmaxf(dsum, 1e-20f);
}

extern "C" void kernel_launch(void* const* d_in, const int* in_sizes, int n_in,
                              void* d_out, int out_size, void* d_ws, size_t ws_size,
                              hipStream_t stream)
{
    const float* h     = (const float*)d_in[0];
    const int*   esrc  = (const int*)d_in[1];
    const int*   edst  = (const int*)d_in[2];
    const float* Wfc   = (const float*)d_in[4];
    const float* Wattn = (const float*)d_in[5];
    float* out = (float*)d_out;

    const int n_w = in_sizes[0] / IN_DIM;   // 100000
    const int n_e = in_sizes[1];            // 1600000
    const int n_p = out_size / OUT_DIM;     // 50000

    // workspace layout
    __hip_bfloat16* z = (__hip_bfloat16*)d_ws;                // n_w * 64 (bf16)
    float* s          = (float*)(z + (size_t)n_w * OUT_DIM);  // n_w
    float* sorted_e   = s + n_w;                              // n_e
    int*   sorted_src = (int*)(sorted_e + n_e);               // n_e
    int*   cnt        = sorted_src + n_e;                     // n_p
    int*   off        = cnt + n_p;                            // n_p + 1
    int*   woff       = off + n_p + 1;                        // n_p

    hipMemsetAsync(cnt, 0, (size_t)n_p * sizeof(int), stream);

    const int gemm_blocks = (n_w + 127) / 128;
    gemm_s_kernel<<<gemm_blocks, 1024, 0, stream>>>(h, Wfc, Wattn, z, s, n_w);
    hist_kernel<<<2048, 256, 0, stream>>>(edst, cnt, n_e);
    scan_kernel<<<1, 1024, 0, stream>>>(cnt, off, woff, n_p);
    bin_kernel<<<2048, 256, 0, stream>>>(esrc, edst, s, woff, sorted_src, sorted_e, n_e);
    segment_kernel<<<(n_p + 3) / 4, 256, 0, stream>>>(off, sorted_src, sorted_e, z, out, n_p);
}

// Round 4
// 524.495 us; speedup vs baseline: 1.5575x; 1.5575x over previous
//
#include <hip/hip_runtime.h>
#include <hip/hip_bf16.h>
#include <math.h>

#define IN_DIM 256
#define OUT_DIM 64
#define KT 132           // padded LDS row stride (floats): 528B, 16B-aligned, stride%32==4
#define ROWS_PER_WAVE 8
#define ROWS_PER_BLOCK 32

__device__ __forceinline__ float edge_score(float x) {
    float e = x > 0.0f ? x : 0.01f * x;   // leaky_relu, slope 0.01
    if (e == 0.0f) e = -1000.0f;          // where(e==0, -1000, e)
    return e;
}

// z = h @ W_fc, s[row] = dot(z[row], W_attn[:64])
// W^T staged in LDS in two 128-K halves (33KB -> 4 blocks/CU).
// 8 rows per wave; h rows loaded via wave-uniform scalar loads.
__global__ __launch_bounds__(256, 4) void gemm_s_kernel(
    const float* __restrict__ h, const float* __restrict__ Wfc,
    const float* __restrict__ Wattn, __hip_bfloat16* __restrict__ z,
    float* __restrict__ s, int n_rows)
{
    __shared__ float WT[OUT_DIM * KT];     // [d][kk], kk in [0,128)
    const int tid = threadIdx.x;
    const int lane = tid & 63;
    const int wv = __builtin_amdgcn_readfirstlane(tid >> 6);
    const float a = Wattn[lane];

    const int row0 = blockIdx.x * ROWS_PER_BLOCK + wv * ROWS_PER_WAVE;

    // wave-uniform clamped row pointers (scalar)
    const float* hp[ROWS_PER_WAVE];
    #pragma unroll
    for (int r = 0; r < ROWS_PER_WAVE; ++r) {
        int rowc = min(row0 + r, n_rows - 1);
        hp[r] = h + (size_t)rowc * IN_DIM;
    }

    float acc[ROWS_PER_WAVE];
    #pragma unroll
    for (int r = 0; r < ROWS_PER_WAVE; ++r) acc[r] = 0.0f;

    for (int stage = 0; stage < 2; ++stage) {
        // stage W^T[d][kk] for k = stage*128 + kk
        __syncthreads();   // protect previous stage's reads
        {
            const int d = tid & 63;
            const int k0 = tid >> 6;       // 0..3
            #pragma unroll
            for (int i = 0; i < 32; ++i) {
                const int kk = k0 + i * 4;
                WT[d * KT + kk] = Wfc[(size_t)(stage * 128 + kk) * OUT_DIM + d];
            }
        }
        __syncthreads();

        const float4* WT4 = (const float4*)&WT[lane * KT];

        #pragma unroll 2
        for (int k4 = 0; k4 < 32; ++k4) {
            const float4 w4 = WT4[k4];
            #pragma unroll
            for (int r = 0; r < ROWS_PER_WAVE; ++r) {
                const float4 hv = ((const float4*)(hp[r] + stage * 128))[k4];
                acc[r] = fmaf(hv.w, w4.w, fmaf(hv.z, w4.z,
                         fmaf(hv.y, w4.y, fmaf(hv.x, w4.x, acc[r]))));
            }
        }
    }

    #pragma unroll
    for (int r = 0; r < ROWS_PER_WAVE; ++r) {
        const int row = row0 + r;
        if (row < n_rows)
            z[(size_t)row * OUT_DIM + lane] = __float2bfloat16(acc[r]);
        float p = acc[r] * a;
        #pragma unroll
        for (int o = 32; o > 0; o >>= 1) p += __shfl_xor(p, o);
        if (lane == 0 && row < n_rows) s[row] = p;
    }
}

// count[dst]++
__global__ __launch_bounds__(256) void hist_kernel(
    const int* __restrict__ dst, int* __restrict__ cnt, int n_edges)
{
    int i = blockIdx.x * blockDim.x + threadIdx.x;
    int stride = gridDim.x * blockDim.x;
    for (; i < n_edges; i += stride) atomicAdd(cnt + dst[i], 1);
}

// single-block exclusive scan of cnt[0..n) -> off[] and woff[]; off[n]=total
__global__ __launch_bounds__(1024) void scan_kernel(
    const int* __restrict__ cnt, int* __restrict__ off, int* __restrict__ woff, int n)
{
    __shared__ int ssum[1024];
    const int t = threadIdx.x;
    const int chunk = (n + 1023) >> 10;
    const int b = t * chunk;
    const int e = min(b + chunk, n);
    int local = 0;
    for (int i = b; i < e; ++i) local += cnt[i];
    ssum[t] = local;
    __syncthreads();
    for (int d = 1; d < 1024; d <<= 1) {
        int v = (t >= d) ? ssum[t - d] : 0;
        __syncthreads();
        ssum[t] += v;
        __syncthreads();
    }
    int run = ssum[t] - local;
    for (int i = b; i < e; ++i) {
        off[i] = run; woff[i] = run;
        run += cnt[i];
    }
    if (t == 1023) off[n] = ssum[1023];
}

// bin edges by dst; also precompute per-edge score e
__global__ __launch_bounds__(256) void bin_kernel(
    const int* __restrict__ src, const int* __restrict__ dst,
    const float* __restrict__ s, int* __restrict__ woff,
    int* __restrict__ sorted_src, float* __restrict__ sorted_e, int n_edges)
{
    int i = blockIdx.x * blockDim.x + threadIdx.x;
    int stride = gridDim.x * blockDim.x;
    for (; i < n_edges; i += stride) {
        int sr = src[i];
        float e = edge_score(s[sr]);
        int pos = atomicAdd(woff + dst[i], 1);
        sorted_src[pos] = sr;
        sorted_e[pos] = e;
    }
}

// one wave per pnode: softmax over its contiguous edge segment + weighted z-sum
__global__ __launch_bounds__(256) void segment_kernel(
    const int* __restrict__ off, const int* __restrict__ sorted_src,
    const float* __restrict__ sorted_e, const __hip_bfloat16* __restrict__ z,
    float* __restrict__ out, int n_pnodes)
{
    const int p = blockIdx.x * 4 + (threadIdx.x >> 6);
    if (p >= n_pnodes) return;
    const int lane = threadIdx.x & 63;
    const int beg = off[p];
    const int end = off[p + 1];

    if (beg == end) {
        out[(size_t)p * OUT_DIM + lane] = 0.0f;
        return;
    }

    float m = -INFINITY;
    for (int j = beg + lane; j < end; j += 64) m = fmaxf(m, sorted_e[j]);
    #pragma unroll
    for (int o = 32; o > 0; o >>= 1) m = fmaxf(m, __shfl_xor(m, o));

    float acc = 0.0f, dsum = 0.0f;
    for (int c = beg; c < end; c += 64) {
        const int j = c + lane;
        const bool v = j < end;
        float w = 0.0f;
        int sr = 0;
        if (v) {
            w = __expf(sorted_e[j] - m);
            sr = sorted_src[j];
        }
        dsum += w;
        const int cn = min(64, end - c);
        for (int t = 0; t < cn; ++t) {
            float wt = __shfl(w, t);
            int st = __shfl(sr, t);
            acc = fmaf(wt, __bfloat162float(z[(size_t)st * OUT_DIM + lane]), acc);
        }
    }
    #pragma unroll
    for (int o = 32; o > 0; o >>= 1) dsum += __shfl_xor(dsum, o);
    out[(size_t)p * OUT_DIM + lane] = acc / fmaxf(dsum, 1e-20f);
}

extern "C" void kernel_launch(void* const* d_in, const int* in_sizes, int n_in,
                              void* d_out, int out_size, void* d_ws, size_t ws_size,
                              hipStream_t stream)
{
    const float* h     = (const float*)d_in[0];
    const int*   esrc  = (const int*)d_in[1];
    const int*   edst  = (const int*)d_in[2];
    const float* Wfc   = (const float*)d_in[4];
    const float* Wattn = (const float*)d_in[5];
    float* out = (float*)d_out;

    const int n_w = in_sizes[0] / IN_DIM;   // 100000
    const int n_e = in_sizes[1];            // 1600000
    const int n_p = out_size / OUT_DIM;     // 50000

    // workspace layout
    __hip_bfloat16* z = (__hip_bfloat16*)d_ws;                // n_w * 64 (bf16)
    float* s          = (float*)(z + (size_t)n_w * OUT_DIM);  // n_w
    float* sorted_e   = s + n_w;                              // n_e
    int*   sorted_src = (int*)(sorted_e + n_e);               // n_e
    int*   cnt        = sorted_src + n_e;                     // n_p
    int*   off        = cnt + n_p;                            // n_p + 1
    int*   woff       = off + n_p + 1;                        // n_p

    hipMemsetAsync(cnt, 0, (size_t)n_p * sizeof(int), stream);

    const int gemm_blocks = (n_w + ROWS_PER_BLOCK - 1) / ROWS_PER_BLOCK;
    gemm_s_kernel<<<gemm_blocks, 256, 0, stream>>>(h, Wfc, Wattn, z, s, n_w);
    hist_kernel<<<2048, 256, 0, stream>>>(edst, cnt, n_e);
    scan_kernel<<<1, 1024, 0, stream>>>(cnt, off, woff, n_p);
    bin_kernel<<<2048, 256, 0, stream>>>(esrc, edst, s, woff, sorted_src, sorted_e, n_e);
    segment_kernel<<<(n_p + 3) / 4, 256, 0, stream>>>(off, sorted_src, sorted_e, z, out, n_p);
}

// Round 5
// 388.410 us; speedup vs baseline: 2.1032x; 1.3504x over previous
//
#include <hip/hip_runtime.h>
#include <math.h>

#define IN_DIM 256
#define OUT_DIM 64

typedef __attribute__((ext_vector_type(8))) short short8v;   // 8 bf16 (4 VGPRs)
typedef __attribute__((ext_vector_type(4))) float f32x4;     // MFMA acc

__device__ __forceinline__ unsigned short f2bf(float f) {
    unsigned u = __float_as_uint(f);
    unsigned r = (u + 0x7fffu + ((u >> 16) & 1u)) >> 16;     // RTNE
    return (unsigned short)r;
}

__device__ __forceinline__ float bf2f(unsigned short b) {
    return __uint_as_float(((unsigned)b) << 16);
}

__device__ __forceinline__ float edge_score(float x) {
    float e = x > 0.0f ? x : 0.01f * x;   // leaky_relu, slope 0.01
    if (e == 0.0f) e = -1000.0f;          // where(e==0, -1000, e)
    return e;
}

// Pre-pack W_fc (256x64 f32) into MFMA B-fragments, bf16.
// Frag v = (ks*4+t)*64 + lane holds W[k = ks*32 + (lane>>4)*8 + j][t*16 + (lane&15)].
__global__ __launch_bounds__(256) void prep_kernel(
    const float* __restrict__ Wfc, short8v* __restrict__ wtf)
{
    const int v0 = threadIdx.x;
    for (int it = 0; it < 8; ++it) {
        const int v = v0 + it * 256;          // 0..2047
        const int ks = v >> 8;
        const int t = (v >> 6) & 3;
        const int lane = v & 63;
        const int lg = lane >> 4, lr = lane & 15;
        short8v b;
        #pragma unroll
        for (int j = 0; j < 8; ++j) {
            const int k = ks * 32 + lg * 8 + j;
            b[j] = (short)f2bf(Wfc[k * OUT_DIM + t * 16 + lr]);
        }
        wtf[v] = b;
    }
}

// z = h @ W_fc via MFMA (B in VGPRs, no LDS), s[row] = dot(z_row, W_attn[:64]).
// Wave computes 16 rows x 64 dims. Fused: dst histogram for the sort.
__global__ __launch_bounds__(256, 2) void gemm_s_kernel(
    const float* __restrict__ h, const short8v* __restrict__ wtf,
    const float* __restrict__ Wattn, const int* __restrict__ edst,
    unsigned short* __restrict__ z, float* __restrict__ s,
    int* __restrict__ cnt, int n_rows, int n_edges)
{
    const int tid = threadIdx.x;
    const int lane = tid & 63;
    const int wv = tid >> 6;
    const int lg = lane >> 4;       // lane group 0..3 (k-slot group)
    const int lr = lane & 15;       // A-row / B-col / C-col within tile

    // preload all B fragments: 8 K-steps x 4 d-tiles (128 VGPRs)
    short8v Bf[8][4];
    #pragma unroll
    for (int ks = 0; ks < 8; ++ks)
        #pragma unroll
        for (int t = 0; t < 4; ++t)
            Bf[ks][t] = wtf[(ks * 4 + t) * 64 + lane];

    float a_attn[4];
    #pragma unroll
    for (int t = 0; t < 4; ++t) a_attn[t] = Wattn[t * 16 + lr];

    const int row0 = blockIdx.x * 64 + wv * 16;
    const float* hrow = h + (size_t)min(row0 + lr, n_rows - 1) * IN_DIM;

    f32x4 acc[4];
    #pragma unroll
    for (int t = 0; t < 4; ++t) acc[t] = (f32x4){0.f, 0.f, 0.f, 0.f};

    #pragma unroll
    for (int ks = 0; ks < 8; ++ks) {
        const float4 x0 = *(const float4*)(hrow + ks * 32 + lg * 8);
        const float4 x1 = *(const float4*)(hrow + ks * 32 + lg * 8 + 4);
        short8v af;
        af[0] = (short)f2bf(x0.x); af[1] = (short)f2bf(x0.y);
        af[2] = (short)f2bf(x0.z); af[3] = (short)f2bf(x0.w);
        af[4] = (short)f2bf(x1.x); af[5] = (short)f2bf(x1.y);
        af[6] = (short)f2bf(x1.z); af[7] = (short)f2bf(x1.w);
        #pragma unroll
        for (int t = 0; t < 4; ++t)
            acc[t] = __builtin_amdgcn_mfma_f32_16x16x32_bf16(af, Bf[ks][t], acc[t], 0, 0, 0);
    }

    // epilogue: C/D layout col = lane&15 (dim within tile), row = lg*4 + j
    #pragma unroll
    for (int j = 0; j < 4; ++j) {
        const int row = row0 + lg * 4 + j;
        const bool ok = row < n_rows;
        float sv = 0.0f;
        #pragma unroll
        for (int t = 0; t < 4; ++t) {
            const float v = acc[t][j];
            if (ok) z[(size_t)row * OUT_DIM + t * 16 + lr] = f2bf(v);
            sv = fmaf(v, a_attn[t], sv);
        }
        #pragma unroll
        for (int o = 1; o < 16; o <<= 1) sv += __shfl_xor(sv, o);
        if (ok && lr == 0) s[row] = sv;
    }

    // fused dst histogram
    const int gstride = gridDim.x * blockDim.x;
    for (int i = blockIdx.x * blockDim.x + tid; i < n_edges; i += gstride)
        atomicAdd(cnt + edst[i], 1);
}

// single-block exclusive scan of cnt[0..n) -> off[] and woff[]; off[n]=total
__global__ __launch_bounds__(1024) void scan_kernel(
    const int* __restrict__ cnt, int* __restrict__ off, int* __restrict__ woff, int n)
{
    __shared__ int ssum[1024];
    const int t = threadIdx.x;
    const int chunk = (n + 1023) >> 10;
    const int b = t * chunk;
    const int e = min(b + chunk, n);
    int local = 0;
    for (int i = b; i < e; ++i) local += cnt[i];
    ssum[t] = local;
    __syncthreads();
    for (int d = 1; d < 1024; d <<= 1) {
        int v = (t >= d) ? ssum[t - d] : 0;
        __syncthreads();
        ssum[t] += v;
        __syncthreads();
    }
    int run = ssum[t] - local;
    for (int i = b; i < e; ++i) {
        off[i] = run; woff[i] = run;
        run += cnt[i];
    }
    if (t == 1023) off[n] = ssum[1023];
}

// bin edges by dst; packed (src, e) 8B records
__global__ __launch_bounds__(256) void bin_kernel(
    const int* __restrict__ src, const int* __restrict__ dst,
    const float* __restrict__ s, int* __restrict__ woff,
    int2* __restrict__ sorted_pk, int n_edges)
{
    int i = blockIdx.x * blockDim.x + threadIdx.x;
    int stride = gridDim.x * blockDim.x;
    for (; i < n_edges; i += stride) {
        int sr = src[i];
        float e = edge_score(s[sr]);
        int pos = atomicAdd(woff + dst[i], 1);
        int2 pk; pk.x = sr; pk.y = __float_as_int(e);
        sorted_pk[pos] = pk;
    }
}

// one wave per pnode: softmax over its contiguous segment + weighted z-sum
__global__ __launch_bounds__(256) void segment_kernel(
    const int* __restrict__ off, const int2* __restrict__ sorted_pk,
    const unsigned short* __restrict__ z, float* __restrict__ out, int n_pnodes)
{
    const int p = blockIdx.x * 4 + (threadIdx.x >> 6);
    if (p >= n_pnodes) return;
    const int lane = threadIdx.x & 63;
    const int beg = off[p];
    const int end = off[p + 1];

    if (beg == end) {
        out[(size_t)p * OUT_DIM + lane] = 0.0f;
        return;
    }

    float m = -INFINITY;
    for (int j = beg + lane; j < end; j += 64)
        m = fmaxf(m, __int_as_float(sorted_pk[j].y));
    #pragma unroll
    for (int o = 32; o > 0; o >>= 1) m = fmaxf(m, __shfl_xor(m, o));

    float acc = 0.0f, dsum = 0.0f;
    for (int c = beg; c < end; c += 64) {
        const int j = c + lane;
        float w = 0.0f;
        int sr = 0;
        if (j < end) {
            int2 v = sorted_pk[j];
            w = __expf(__int_as_float(v.y) - m);
            sr = v.x;
        }
        dsum += w;
        const int cn = min(64, end - c);
        for (int t = 0; t < cn; ++t) {
            float wt = __shfl(w, t);
            int st = __shfl(sr, t);
            acc = fmaf(wt, bf2f(z[(size_t)st * OUT_DIM + lane]), acc);
        }
    }
    #pragma unroll
    for (int o = 32; o > 0; o >>= 1) dsum += __shfl_xor(dsum, o);
    out[(size_t)p * OUT_DIM + lane] = acc / fmaxf(dsum, 1e-20f);
}

extern "C" void kernel_launch(void* const* d_in, const int* in_sizes, int n_in,
                              void* d_out, int out_size, void* d_ws, size_t ws_size,
                              hipStream_t stream)
{
    const float* h     = (const float*)d_in[0];
    const int*   esrc  = (const int*)d_in[1];
    const int*   edst  = (const int*)d_in[2];
    const float* Wfc   = (const float*)d_in[4];
    const float* Wattn = (const float*)d_in[5];
    float* out = (float*)d_out;

    const int n_w = in_sizes[0] / IN_DIM;   // 100000
    const int n_e = in_sizes[1];            // 1600000
    const int n_p = out_size / OUT_DIM;     // 50000

    // workspace layout (wtf first: 16B aligned)
    short8v* wtf            = (short8v*)d_ws;                          // 2048 frags (32 KB)
    unsigned short* z       = (unsigned short*)(wtf + 2048);           // n_w*64 bf16 bits
    float* s                = (float*)(z + (size_t)n_w * OUT_DIM);     // n_w
    int2* sorted_pk         = (int2*)(s + n_w);                        // n_e (8B each)
    int* cnt                = (int*)(sorted_pk + n_e);                 // n_p
    int* off                = cnt + n_p;                               // n_p + 1
    int* woff               = off + n_p + 1;                           // n_p

    hipMemsetAsync(cnt, 0, (size_t)n_p * sizeof(int), stream);

    prep_kernel<<<1, 256, 0, stream>>>(Wfc, wtf);
    const int gemm_blocks = (n_w + 63) / 64;
    gemm_s_kernel<<<gemm_blocks, 256, 0, stream>>>(h, wtf, Wattn, edst, z, s, cnt, n_w, n_e);
    scan_kernel<<<1, 1024, 0, stream>>>(cnt, off, woff, n_p);
    bin_kernel<<<2048, 256, 0, stream>>>(esrc, edst, s, woff, sorted_pk, n_e);
    segment_kernel<<<(n_p + 3) / 4, 256, 0, stream>>>(off, sorted_pk, z, out, n_p);
}

// Round 6
// 272.904 us; speedup vs baseline: 2.9934x; 1.4232x over previous
//
#include <hip/hip_runtime.h>
#include <math.h>

#define IN_DIM 256
#define OUT_DIM 64
#define CHUNK_LOG2 12          // 4096 edges per bin block / label chunk
#define NXCD 8

typedef __attribute__((ext_vector_type(8))) short short8v;   // 8 bf16 (4 VGPRs)
typedef __attribute__((ext_vector_type(4))) float f32x4;     // MFMA acc

__device__ __forceinline__ unsigned short f2bf(float f) {
    unsigned u = __float_as_uint(f);
    unsigned r = (u + 0x7fffu + ((u >> 16) & 1u)) >> 16;     // RTNE
    return (unsigned short)r;
}

__device__ __forceinline__ float bf2f(unsigned short b) {
    return __uint_as_float(((unsigned)b) << 16);
}

__device__ __forceinline__ float edge_score(float x) {
    float e = x > 0.0f ? x : 0.01f * x;   // leaky_relu, slope 0.01
    if (e == 0.0f) e = -1000.0f;          // where(e==0, -1000, e)
    return e;
}

// Pre-pack W_fc (256x64 f32) into MFMA B-fragments, bf16.
__global__ __launch_bounds__(256) void prep_kernel(
    const float* __restrict__ Wfc, short8v* __restrict__ wtf)
{
    const int v0 = threadIdx.x;
    for (int it = 0; it < 8; ++it) {
        const int v = v0 + it * 256;          // 0..2047
        const int ks = v >> 8;
        const int t = (v >> 6) & 3;
        const int lane = v & 63;
        const int lg = lane >> 4, lr = lane & 15;
        short8v b;
        #pragma unroll
        for (int j = 0; j < 8; ++j) {
            const int k = ks * 32 + lg * 8 + j;
            b[j] = (short)f2bf(Wfc[k * OUT_DIM + t * 16 + lr]);
        }
        wtf[v] = b;
    }
}

// z = h @ W_fc via MFMA (B in VGPRs, no LDS), s[row] = dot(z_row, W_attn[:64]).
// Fused: XCD-labeled dst histogram cnt[dst*8 + (i>>12)&7]++.
__global__ __launch_bounds__(256, 2) void gemm_s_kernel(
    const float* __restrict__ h, const short8v* __restrict__ wtf,
    const float* __restrict__ Wattn, const int* __restrict__ edst,
    unsigned short* __restrict__ z, float* __restrict__ s,
    int* __restrict__ cnt, int n_rows, int n_edges)
{
    const int tid = threadIdx.x;
    const int lane = tid & 63;
    const int wv = tid >> 6;
    const int lg = lane >> 4;
    const int lr = lane & 15;

    short8v Bf[8][4];
    #pragma unroll
    for (int ks = 0; ks < 8; ++ks)
        #pragma unroll
        for (int t = 0; t < 4; ++t)
            Bf[ks][t] = wtf[(ks * 4 + t) * 64 + lane];

    float a_attn[4];
    #pragma unroll
    for (int t = 0; t < 4; ++t) a_attn[t] = Wattn[t * 16 + lr];

    const int row0 = blockIdx.x * 64 + wv * 16;
    const float* hrow = h + (size_t)min(row0 + lr, n_rows - 1) * IN_DIM;

    f32x4 acc[4];
    #pragma unroll
    for (int t = 0; t < 4; ++t) acc[t] = (f32x4){0.f, 0.f, 0.f, 0.f};

    #pragma unroll
    for (int ks = 0; ks < 8; ++ks) {
        const float4 x0 = *(const float4*)(hrow + ks * 32 + lg * 8);
        const float4 x1 = *(const float4*)(hrow + ks * 32 + lg * 8 + 4);
        short8v af;
        af[0] = (short)f2bf(x0.x); af[1] = (short)f2bf(x0.y);
        af[2] = (short)f2bf(x0.z); af[3] = (short)f2bf(x0.w);
        af[4] = (short)f2bf(x1.x); af[5] = (short)f2bf(x1.y);
        af[6] = (short)f2bf(x1.z); af[7] = (short)f2bf(x1.w);
        #pragma unroll
        for (int t = 0; t < 4; ++t)
            acc[t] = __builtin_amdgcn_mfma_f32_16x16x32_bf16(af, Bf[ks][t], acc[t], 0, 0, 0);
    }

    #pragma unroll
    for (int j = 0; j < 4; ++j) {
        const int row = row0 + lg * 4 + j;
        const bool ok = row < n_rows;
        float sv = 0.0f;
        #pragma unroll
        for (int t = 0; t < 4; ++t) {
            const float v = acc[t][j];
            if (ok) z[(size_t)row * OUT_DIM + t * 16 + lr] = f2bf(v);
            sv = fmaf(v, a_attn[t], sv);
        }
        #pragma unroll
        for (int o = 1; o < 16; o <<= 1) sv += __shfl_xor(sv, o);
        if (ok && lr == 0) s[row] = sv;
    }

    // fused labeled histogram
    const int gstride = gridDim.x * blockDim.x;
    for (int i = blockIdx.x * blockDim.x + tid; i < n_edges; i += gstride) {
        const int x = (i >> CHUNK_LOG2) & (NXCD - 1);
        atomicAdd(cnt + edst[i] * NXCD + x, 1);
    }
}

// ---- 3-stage multi-block exclusive scan over N8 = n_p*8 counters ----
__global__ __launch_bounds__(1024) void scanA_kernel(
    const int* __restrict__ cnt, int* __restrict__ off, int* __restrict__ bsum, int n)
{
    __shared__ int ssum[1024];
    const int t = threadIdx.x;
    const int g = blockIdx.x * 1024 + t;
    const int val = (g < n) ? cnt[g] : 0;
    ssum[t] = val;
    __syncthreads();
    for (int d = 1; d < 1024; d <<= 1) {
        int v = (t >= d) ? ssum[t - d] : 0;
        __syncthreads();
        ssum[t] += v;
        __syncthreads();
    }
    if (g < n) off[g] = ssum[t] - val;       // local exclusive
    if (t == 1023) bsum[blockIdx.x] = ssum[1023];
}

__global__ __launch_bounds__(512) void scanB_kernel(
    int* __restrict__ bsum, int* __restrict__ off, int nb, int n)
{
    __shared__ int ssum[512];
    const int t = threadIdx.x;
    const int val = (t < nb) ? bsum[t] : 0;
    ssum[t] = val;
    __syncthreads();
    for (int d = 1; d < 512; d <<= 1) {
        int v = (t >= d) ? ssum[t - d] : 0;
        __syncthreads();
        ssum[t] += v;
        __syncthreads();
    }
    if (t < nb) bsum[t] = ssum[t] - val;     // exclusive block offsets
    if (t == 511) off[n] = ssum[511];        // grand total
}

__global__ __launch_bounds__(1024) void scanC_kernel(
    int* __restrict__ off, int* __restrict__ woff,
    const int* __restrict__ bsum, int n)
{
    const int g = blockIdx.x * 1024 + threadIdx.x;
    if (g < n) {
        const int v = off[g] + bsum[blockIdx.x];
        off[g] = v;
        woff[g] = v;
    }
}

// bin edges by (dst, chunk-label); block b owns edges [b*4096, (b+1)*4096)
__global__ __launch_bounds__(256) void bin_kernel(
    const int* __restrict__ src, const int* __restrict__ dst,
    const float* __restrict__ s, int* __restrict__ woff,
    int2* __restrict__ sorted_pk, int n_edges)
{
    const int b = blockIdx.x;
    const int x = b & (NXCD - 1);
    const int i0 = b << CHUNK_LOG2;
    const int i1 = min(i0 + (1 << CHUNK_LOG2), n_edges);
    for (int i = i0 + threadIdx.x; i < i1; i += 256) {
        const int sr = src[i];
        const float e = edge_score(s[sr]);
        const int pos = atomicAdd(woff + dst[i] * NXCD + x, 1);
        int2 pk; pk.x = sr; pk.y = __float_as_int(e);
        sorted_pk[pos] = pk;
    }
}

// one wave per pnode: softmax over its contiguous segment + weighted z-sum
__global__ __launch_bounds__(256) void segment_kernel(
    const int* __restrict__ off, const int2* __restrict__ sorted_pk,
    const unsigned short* __restrict__ z, float* __restrict__ out, int n_pnodes)
{
    const int p = blockIdx.x * 4 + (threadIdx.x >> 6);
    if (p >= n_pnodes) return;
    const int lane = threadIdx.x & 63;
    const int beg = off[p * NXCD];
    const int end = off[p * NXCD + NXCD];   // == off[(p+1)*NXCD], contiguous

    if (beg == end) {
        out[(size_t)p * OUT_DIM + lane] = 0.0f;
        return;
    }

    float m = -INFINITY;
    for (int j = beg + lane; j < end; j += 64)
        m = fmaxf(m, __int_as_float(sorted_pk[j].y));
    #pragma unroll
    for (int o = 32; o > 0; o >>= 1) m = fmaxf(m, __shfl_xor(m, o));

    float acc = 0.0f, dsum = 0.0f;
    for (int c = beg; c < end; c += 64) {
        const int j = c + lane;
        float w = 0.0f;
        int sr = 0;
        if (j < end) {
            int2 v = sorted_pk[j];
            w = __expf(__int_as_float(v.y) - m);
            sr = v.x;
        }
        dsum += w;
        const int cn = min(64, end - c);
        for (int t = 0; t < cn; ++t) {
            float wt = __shfl(w, t);
            int st = __shfl(sr, t);
            acc = fmaf(wt, bf2f(z[(size_t)st * OUT_DIM + lane]), acc);
        }
    }
    #pragma unroll
    for (int o = 32; o > 0; o >>= 1) dsum += __shfl_xor(dsum, o);
    out[(size_t)p * OUT_DIM + lane] = acc / fmaxf(dsum, 1e-20f);
}

extern "C" void kernel_launch(void* const* d_in, const int* in_sizes, int n_in,
                              void* d_out, int out_size, void* d_ws, size_t ws_size,
                              hipStream_t stream)
{
    const float* h     = (const float*)d_in[0];
    const int*   esrc  = (const int*)d_in[1];
    const int*   edst  = (const int*)d_in[2];
    const float* Wfc   = (const float*)d_in[4];
    const float* Wattn = (const float*)d_in[5];
    float* out = (float*)d_out;

    const int n_w = in_sizes[0] / IN_DIM;   // 100000
    const int n_e = in_sizes[1];            // 1600000
    const int n_p = out_size / OUT_DIM;     // 50000
    const int N8  = n_p * NXCD;             // 400000 sub-bins

    // workspace layout (wtf first: 16B aligned)
    short8v* wtf            = (short8v*)d_ws;                          // 2048 frags (32 KB)
    unsigned short* z       = (unsigned short*)(wtf + 2048);           // n_w*64 bf16 bits
    float* s                = (float*)(z + (size_t)n_w * OUT_DIM);     // n_w
    int2* sorted_pk         = (int2*)(s + n_w);                        // n_e (8B each)
    int* cnt                = (int*)(sorted_pk + n_e);                 // N8
    int* off                = cnt + N8;                                // N8 + 1
    int* woff               = off + N8 + 1;                            // N8
    int* bsum               = woff + N8;                               // <=512

    hipMemsetAsync(cnt, 0, (size_t)N8 * sizeof(int), stream);

    prep_kernel<<<1, 256, 0, stream>>>(Wfc, wtf);
    const int gemm_blocks = (n_w + 63) / 64;
    gemm_s_kernel<<<gemm_blocks, 256, 0, stream>>>(h, wtf, Wattn, edst, z, s, cnt, n_w, n_e);

    const int nbA = (N8 + 1023) / 1024;     // 391 <= 512
    scanA_kernel<<<nbA, 1024, 0, stream>>>(cnt, off, bsum, N8);
    scanB_kernel<<<1, 512, 0, stream>>>(bsum, off, nbA, N8);
    scanC_kernel<<<nbA, 1024, 0, stream>>>(off, woff, bsum, N8);

    const int nbBin = (n_e + (1 << CHUNK_LOG2) - 1) >> CHUNK_LOG2;
    bin_kernel<<<nbBin, 256, 0, stream>>>(esrc, edst, s, woff, sorted_pk, n_e);
    segment_kernel<<<(n_p + 3) / 4, 256, 0, stream>>>(off, sorted_pk, z, out, n_p);
}

// Round 7
// 221.928 us; speedup vs baseline: 3.6810x; 1.2297x over previous
//
#include <hip/hip_runtime.h>
#include <hip/hip_bf16.h>
#include <math.h>

#define IN_DIM 256
#define OUT_DIM 64
#define CHUNK_LOG2 12          // 4096 edges per bin block / label chunk
#define NXCD 8

typedef __attribute__((ext_vector_type(8))) short short8v;   // 8 bf16 (4 VGPRs)
typedef __attribute__((ext_vector_type(4))) float f32x4;     // MFMA acc

__device__ __forceinline__ unsigned short f2bf(float f) {
    unsigned u = __float_as_uint(f);
    unsigned r = (u + 0x7fffu + ((u >> 16) & 1u)) >> 16;     // RTNE
    return (unsigned short)r;
}

__device__ __forceinline__ float bf2f(unsigned short b) {
    return __uint_as_float(((unsigned)b) << 16);
}

__device__ __forceinline__ float edge_score(float x) {
    float e = x > 0.0f ? x : 0.01f * x;   // leaky_relu, slope 0.01
    if (e == 0.0f) e = -1000.0f;          // where(e==0, -1000, e)
    return e;
}

// Pre-pack W_fc (256x64 f32) into MFMA B-fragments, bf16.
__global__ __launch_bounds__(256) void prep_kernel(
    const float* __restrict__ Wfc, short8v* __restrict__ wtf)
{
    const int v0 = threadIdx.x;
    for (int it = 0; it < 8; ++it) {
        const int v = v0 + it * 256;          // 0..2047
        const int ks = v >> 8;
        const int t = (v >> 6) & 3;
        const int lane = v & 63;
        const int lg = lane >> 4, lr = lane & 15;
        short8v b;
        #pragma unroll
        for (int j = 0; j < 8; ++j) {
            const int k = ks * 32 + lg * 8 + j;
            b[j] = (short)f2bf(Wfc[k * OUT_DIM + t * 16 + lr]);
        }
        wtf[v] = b;
    }
}

// z = h @ W_fc via MFMA (B in VGPRs/AGPRs, no LDS), s = dot(z_row, W_attn[:64]).
// All 16 h-loads hoisted -> deep vmcnt pipeline. Fused labeled dst histogram.
__global__ __launch_bounds__(256) void gemm_s_kernel(
    const float* __restrict__ h, const short8v* __restrict__ wtf,
    const float* __restrict__ Wattn, const int* __restrict__ edst,
    unsigned short* __restrict__ z, float* __restrict__ s,
    int* __restrict__ cnt, int n_rows, int n_edges)
{
    const int tid = threadIdx.x;
    const int lane = tid & 63;
    const int wv = tid >> 6;
    const int lg = lane >> 4;
    const int lr = lane & 15;

    short8v Bf[8][4];
    #pragma unroll
    for (int ks = 0; ks < 8; ++ks)
        #pragma unroll
        for (int t = 0; t < 4; ++t)
            Bf[ks][t] = wtf[(ks * 4 + t) * 64 + lane];

    float a_attn[4];
    #pragma unroll
    for (int t = 0; t < 4; ++t) a_attn[t] = Wattn[t * 16 + lr];

    const int row0 = blockIdx.x * 64 + wv * 16;
    const float* hrow = h + (size_t)min(row0 + lr, n_rows - 1) * IN_DIM;

    // hoist all 16 loads (8 ks x 32B)
    float4 xv[16];
    #pragma unroll
    for (int ks = 0; ks < 8; ++ks) {
        xv[2 * ks]     = *(const float4*)(hrow + ks * 32 + lg * 8);
        xv[2 * ks + 1] = *(const float4*)(hrow + ks * 32 + lg * 8 + 4);
    }

    f32x4 acc[4];
    #pragma unroll
    for (int t = 0; t < 4; ++t) acc[t] = (f32x4){0.f, 0.f, 0.f, 0.f};

    union AB { short8v v; __hip_bfloat162 h2[4]; };
    #pragma unroll
    for (int ks = 0; ks < 8; ++ks) {
        const float4 x0 = xv[2 * ks];
        const float4 x1 = xv[2 * ks + 1];
        AB u;
        u.h2[0] = __float22bfloat162_rn(float2{x0.x, x0.y});
        u.h2[1] = __float22bfloat162_rn(float2{x0.z, x0.w});
        u.h2[2] = __float22bfloat162_rn(float2{x1.x, x1.y});
        u.h2[3] = __float22bfloat162_rn(float2{x1.z, x1.w});
        #pragma unroll
        for (int t = 0; t < 4; ++t)
            acc[t] = __builtin_amdgcn_mfma_f32_16x16x32_bf16(u.v, Bf[ks][t], acc[t], 0, 0, 0);
    }

    // epilogue: C/D layout col = lane&15, row = lg*4 + j
    #pragma unroll
    for (int j = 0; j < 4; ++j) {
        const int row = row0 + lg * 4 + j;
        const bool ok = row < n_rows;
        float sv = 0.0f;
        #pragma unroll
        for (int t = 0; t < 4; ++t) {
            const float v = acc[t][j];
            if (ok) z[(size_t)row * OUT_DIM + t * 16 + lr] =
                __bfloat16_as_ushort(__float2bfloat16(v));
            sv = fmaf(v, a_attn[t], sv);
        }
        #pragma unroll
        for (int o = 1; o < 16; o <<= 1) sv += __shfl_xor(sv, o);
        if (ok && lr == 0) s[row] = sv;
    }

    // fused labeled histogram
    const int gstride = gridDim.x * blockDim.x;
    for (int i = blockIdx.x * blockDim.x + tid; i < n_edges; i += gstride) {
        const int x = (i >> CHUNK_LOG2) & (NXCD - 1);
        atomicAdd(cnt + edst[i] * NXCD + x, 1);
    }
}

// ---- 3-stage multi-block exclusive scan over N8 = n_p*8 counters ----
__global__ __launch_bounds__(1024) void scanA_kernel(
    const int* __restrict__ cnt, int* __restrict__ off, int* __restrict__ bsum, int n)
{
    __shared__ int ssum[1024];
    const int t = threadIdx.x;
    const int g = blockIdx.x * 1024 + t;
    const int val = (g < n) ? cnt[g] : 0;
    ssum[t] = val;
    __syncthreads();
    for (int d = 1; d < 1024; d <<= 1) {
        int v = (t >= d) ? ssum[t - d] : 0;
        __syncthreads();
        ssum[t] += v;
        __syncthreads();
    }
    if (g < n) off[g] = ssum[t] - val;       // local exclusive
    if (t == 1023) bsum[blockIdx.x] = ssum[1023];
}

__global__ __launch_bounds__(512) void scanB_kernel(
    int* __restrict__ bsum, int* __restrict__ off, int nb, int n)
{
    __shared__ int ssum[512];
    const int t = threadIdx.x;
    const int val = (t < nb) ? bsum[t] : 0;
    ssum[t] = val;
    __syncthreads();
    for (int d = 1; d < 512; d <<= 1) {
        int v = (t >= d) ? ssum[t - d] : 0;
        __syncthreads();
        ssum[t] += v;
        __syncthreads();
    }
    if (t < nb) bsum[t] = ssum[t] - val;     // exclusive block offsets
    if (t == 511) off[n] = ssum[511];        // grand total
}

__global__ __launch_bounds__(1024) void scanC_kernel(
    int* __restrict__ off, int* __restrict__ woff,
    const int* __restrict__ bsum, int n)
{
    const int g = blockIdx.x * 1024 + threadIdx.x;
    if (g < n) {
        const int v = off[g] + bsum[blockIdx.x];
        off[g] = v;
        woff[g] = v;
    }
}

// bin edges by (dst, chunk-label); block b owns edges [b*4096, (b+1)*4096)
__global__ __launch_bounds__(256) void bin_kernel(
    const int* __restrict__ src, const int* __restrict__ dst,
    const float* __restrict__ s, int* __restrict__ woff,
    int2* __restrict__ sorted_pk, int n_edges)
{
    const int b = blockIdx.x;
    const int x = b & (NXCD - 1);
    const int i0 = b << CHUNK_LOG2;
    const int i1 = min(i0 + (1 << CHUNK_LOG2), n_edges);
    for (int i = i0 + threadIdx.x; i < i1; i += 256) {
        const int sr = src[i];
        const float e = edge_score(s[sr]);
        const int pos = atomicAdd(woff + dst[i] * NXCD + x, 1);
        int2 pk; pk.x = sr; pk.y = __float_as_int(e);
        sorted_pk[pos] = pk;
    }
}

// one wave per pnode: softmax over its contiguous segment + weighted z-sum
__global__ __launch_bounds__(256) void segment_kernel(
    const int* __restrict__ off, const int2* __restrict__ sorted_pk,
    const unsigned short* __restrict__ z, float* __restrict__ out, int n_pnodes)
{
    const int p = blockIdx.x * 4 + (threadIdx.x >> 6);
    if (p >= n_pnodes) return;
    const int lane = threadIdx.x & 63;
    const int beg = off[p * NXCD];
    const int end = off[p * NXCD + NXCD];   // contiguous range

    if (beg == end) {
        out[(size_t)p * OUT_DIM + lane] = 0.0f;
        return;
    }

    const int len = end - beg;
    float acc = 0.0f, dsum = 0.0f;

    if (len <= 64) {
        // one-chunk fast path: load each record once
        const int j = beg + lane;
        const bool v = j < end;
        int2 pk = sorted_pk[v ? j : beg];
        float e = v ? __int_as_float(pk.y) : -INFINITY;
        float m = e;
        #pragma unroll
        for (int o = 32; o > 0; o >>= 1) m = fmaxf(m, __shfl_xor(m, o));
        float w = v ? __expf(e - m) : 0.0f;
        int sr = pk.x;
        dsum = w;
        #pragma unroll
        for (int o = 32; o > 0; o >>= 1) dsum += __shfl_xor(dsum, o);

        int t = 0;
        for (; t + 4 <= len; t += 4) {
            float w0 = __shfl(w, t),     w1 = __shfl(w, t + 1);
            float w2 = __shfl(w, t + 2), w3 = __shfl(w, t + 3);
            int   s0 = __shfl(sr, t),     s1 = __shfl(sr, t + 1);
            int   s2 = __shfl(sr, t + 2), s3 = __shfl(sr, t + 3);
            float z0 = bf2f(z[(size_t)s0 * OUT_DIM + lane]);
            float z1 = bf2f(z[(size_t)s1 * OUT_DIM + lane]);
            float z2 = bf2f(z[(size_t)s2 * OUT_DIM + lane]);
            float z3 = bf2f(z[(size_t)s3 * OUT_DIM + lane]);
            acc = fmaf(w0, z0, acc); acc = fmaf(w1, z1, acc);
            acc = fmaf(w2, z2, acc); acc = fmaf(w3, z3, acc);
        }
        for (; t < len; ++t) {
            float wt = __shfl(w, t);
            int st = __shfl(sr, t);
            acc = fmaf(wt, bf2f(z[(size_t)st * OUT_DIM + lane]), acc);
        }
    } else {
        // general two-pass path
        float m = -INFINITY;
        for (int j = beg + lane; j < end; j += 64)
            m = fmaxf(m, __int_as_float(sorted_pk[j].y));
        #pragma unroll
        for (int o = 32; o > 0; o >>= 1) m = fmaxf(m, __shfl_xor(m, o));

        for (int c = beg; c < end; c += 64) {
            const int j = c + lane;
            float w = 0.0f;
            int sr = 0;
            if (j < end) {
                int2 v = sorted_pk[j];
                w = __expf(__int_as_float(v.y) - m);
                sr = v.x;
            }
            dsum += w;
            const int cn = min(64, end - c);
            int t = 0;
            for (; t + 4 <= cn; t += 4) {
                float w0 = __shfl(w, t),     w1 = __shfl(w, t + 1);
                float w2 = __shfl(w, t + 2), w3 = __shfl(w, t + 3);
                int   s0 = __shfl(sr, t),     s1 = __shfl(sr, t + 1);
                int   s2 = __shfl(sr, t + 2), s3 = __shfl(sr, t + 3);
                float z0 = bf2f(z[(size_t)s0 * OUT_DIM + lane]);
                float z1 = bf2f(z[(size_t)s1 * OUT_DIM + lane]);
                float z2 = bf2f(z[(size_t)s2 * OUT_DIM + lane]);
                float z3 = bf2f(z[(size_t)s3 * OUT_DIM + lane]);
                acc = fmaf(w0, z0, acc); acc = fmaf(w1, z1, acc);
                acc = fmaf(w2, z2, acc); acc = fmaf(w3, z3, acc);
            }
            for (; t < cn; ++t) {
                float wt = __shfl(w, t);
                int st = __shfl(sr, t);
                acc = fmaf(wt, bf2f(z[(size_t)st * OUT_DIM + lane]), acc);
            }
        }
        #pragma unroll
        for (int o = 32; o > 0; o >>= 1) dsum += __shfl_xor(dsum, o);
    }

    out[(size_t)p * OUT_DIM + lane] = acc / fmaxf(dsum, 1e-20f);
}

extern "C" void kernel_launch(void* const* d_in, const int* in_sizes, int n_in,
                              void* d_out, int out_size, void* d_ws, size_t ws_size,
                              hipStream_t stream)
{
    const float* h     = (const float*)d_in[0];
    const int*   esrc  = (const int*)d_in[1];
    const int*   edst  = (const int*)d_in[2];
    const float* Wfc   = (const float*)d_in[4];
    const float* Wattn = (const float*)d_in[5];
    float* out = (float*)d_out;

    const int n_w = in_sizes[0] / IN_DIM;   // 100000
    const int n_e = in_sizes[1];            // 1600000
    const int n_p = out_size / OUT_DIM;     // 50000
    const int N8  = n_p * NXCD;             // 400000 sub-bins

    // workspace layout (wtf first: 16B aligned)
    short8v* wtf            = (short8v*)d_ws;                          // 2048 frags (32 KB)
    unsigned short* z       = (unsigned short*)(wtf + 2048);           // n_w*64 bf16 bits
    float* s                = (float*)(z + (size_t)n_w * OUT_DIM);     // n_w
    int2* sorted_pk         = (int2*)(s + n_w);                        // n_e (8B each)
    int* cnt                = (int*)(sorted_pk + n_e);                 // N8
    int* off                = cnt + N8;                                // N8 + 1
    int* woff               = off + N8 + 1;                            // N8
    int* bsum               = woff + N8;                               // <=512

    hipMemsetAsync(cnt, 0, (size_t)N8 * sizeof(int), stream);

    prep_kernel<<<1, 256, 0, stream>>>(Wfc, wtf);
    const int gemm_blocks = (n_w + 63) / 64;
    gemm_s_kernel<<<gemm_blocks, 256, 0, stream>>>(h, wtf, Wattn, edst, z, s, cnt, n_w, n_e);

    const int nbA = (N8 + 1023) / 1024;     // 391 <= 512
    scanA_kernel<<<nbA, 1024, 0, stream>>>(cnt, off, bsum, N8);
    scanB_kernel<<<1, 512, 0, stream>>>(bsum, off, nbA, N8);
    scanC_kernel<<<nbA, 1024, 0, stream>>>(off, woff, bsum, N8);

    const int nbBin = (n_e + (1 << CHUNK_LOG2) - 1) >> CHUNK_LOG2;
    bin_kernel<<<nbBin, 256, 0, stream>>>(esrc, edst, s, woff, sorted_pk, n_e);
    segment_kernel<<<(n_p + 3) / 4, 256, 0, stream>>>(off, sorted_pk, z, out, n_p);
}

// Round 8
// 218.101 us; speedup vs baseline: 3.7456x; 1.0175x over previous
//
#include <hip/hip_runtime.h>
#include <hip/hip_bf16.h>
#include <math.h>

#define IN_DIM 256
#define OUT_DIM 64
#define CHUNK_LOG2 12          // 4096 edges per chunk
#define NXCD 8

typedef __attribute__((ext_vector_type(8))) short short8v;   // 8 bf16 (4 VGPRs)
typedef __attribute__((ext_vector_type(4))) float f32x4;     // MFMA acc

__device__ __forceinline__ unsigned short f2bf(float f) {
    unsigned u = __float_as_uint(f);
    unsigned r = (u + 0x7fffu + ((u >> 16) & 1u)) >> 16;     // RTNE
    return (unsigned short)r;
}

__device__ __forceinline__ float bf2f(unsigned short b) {
    return __uint_as_float(((unsigned)b) << 16);
}

__device__ __forceinline__ float edge_score(float x) {
    float e = x > 0.0f ? x : 0.01f * x;   // leaky_relu, slope 0.01
    if (e == 0.0f) e = -1000.0f;          // where(e==0, -1000, e)
    return e;
}

// Pre-pack W_fc (256x64 f32) into MFMA B-fragments, bf16.
__global__ __launch_bounds__(256) void prep_kernel(
    const float* __restrict__ Wfc, short8v* __restrict__ wtf)
{
    const int v0 = threadIdx.x;
    for (int it = 0; it < 8; ++it) {
        const int v = v0 + it * 256;          // 0..2047
        const int ks = v >> 8;
        const int t = (v >> 6) & 3;
        const int lane = v & 63;
        const int lg = lane >> 4, lr = lane & 15;
        short8v b;
        #pragma unroll
        for (int j = 0; j < 8; ++j) {
            const int k = ks * 32 + lg * 8 + j;
            b[j] = (short)f2bf(Wfc[k * OUT_DIM + t * 16 + lr]);
        }
        wtf[v] = b;
    }
}

// z = h @ W_fc via MFMA (B in regs, no LDS), s = dot(z_row, W_attn[:64]).
// Fused label-major dst histogram: block residue r handles chunks c==r (mod 8),
// bumping cnt[r*n_p + dst] -> XCD-local atomics.
__global__ __launch_bounds__(256) void gemm_s_kernel(
    const float* __restrict__ h, const short8v* __restrict__ wtf,
    const float* __restrict__ Wattn, const int* __restrict__ edst,
    unsigned short* __restrict__ z, float* __restrict__ s,
    int* __restrict__ cnt, int n_rows, int n_edges, int n_p)
{
    const int tid = threadIdx.x;
    const int lane = tid & 63;
    const int wv = tid >> 6;
    const int lg = lane >> 4;
    const int lr = lane & 15;

    short8v Bf[8][4];
    #pragma unroll
    for (int ks = 0; ks < 8; ++ks)
        #pragma unroll
        for (int t = 0; t < 4; ++t)
            Bf[ks][t] = wtf[(ks * 4 + t) * 64 + lane];

    float a_attn[4];
    #pragma unroll
    for (int t = 0; t < 4; ++t) a_attn[t] = Wattn[t * 16 + lr];

    const int row0 = blockIdx.x * 64 + wv * 16;
    const float* hrow = h + (size_t)min(row0 + lr, n_rows - 1) * IN_DIM;

    // hoist all 16 loads (8 ks x 32B)
    float4 xv[16];
    #pragma unroll
    for (int ks = 0; ks < 8; ++ks) {
        xv[2 * ks]     = *(const float4*)(hrow + ks * 32 + lg * 8);
        xv[2 * ks + 1] = *(const float4*)(hrow + ks * 32 + lg * 8 + 4);
    }

    f32x4 acc[4];
    #pragma unroll
    for (int t = 0; t < 4; ++t) acc[t] = (f32x4){0.f, 0.f, 0.f, 0.f};

    union AB { short8v v; __hip_bfloat162 h2[4]; };
    #pragma unroll
    for (int ks = 0; ks < 8; ++ks) {
        const float4 x0 = xv[2 * ks];
        const float4 x1 = xv[2 * ks + 1];
        AB u;
        u.h2[0] = __float22bfloat162_rn(float2{x0.x, x0.y});
        u.h2[1] = __float22bfloat162_rn(float2{x0.z, x0.w});
        u.h2[2] = __float22bfloat162_rn(float2{x1.x, x1.y});
        u.h2[3] = __float22bfloat162_rn(float2{x1.z, x1.w});
        #pragma unroll
        for (int t = 0; t < 4; ++t)
            acc[t] = __builtin_amdgcn_mfma_f32_16x16x32_bf16(u.v, Bf[ks][t], acc[t], 0, 0, 0);
    }

    // epilogue: C/D layout col = lane&15, row = lg*4 + j
    #pragma unroll
    for (int j = 0; j < 4; ++j) {
        const int row = row0 + lg * 4 + j;
        const bool ok = row < n_rows;
        float sv = 0.0f;
        #pragma unroll
        for (int t = 0; t < 4; ++t) {
            const float v = acc[t][j];
            if (ok) z[(size_t)row * OUT_DIM + t * 16 + lr] =
                __bfloat16_as_ushort(__float2bfloat16(v));
            sv = fmaf(v, a_attn[t], sv);
        }
        #pragma unroll
        for (int o = 1; o < 16; o <<= 1) sv += __shfl_xor(sv, o);
        if (ok && lr == 0) s[row] = sv;
    }

    // fused label-major histogram (XCD-local counters)
    const int nchunks = (n_edges + (1 << CHUNK_LOG2) - 1) >> CHUNK_LOG2;
    const int r = blockIdx.x & (NXCD - 1);
    const int nb8 = gridDim.x >> 3;
    int* cbase = cnt + r * n_p;
    for (int c = r + NXCD * (blockIdx.x >> 3); c < nchunks; c += NXCD * nb8) {
        const int i0 = c << CHUNK_LOG2;
        const int i1 = min(i0 + (1 << CHUNK_LOG2), n_edges);
        for (int i = i0 + tid; i < i1; i += 256)
            atomicAdd(cbase + edst[i], 1);
    }
}

// ---- 3-stage multi-block exclusive scan over N8 = n_p*8 counters ----
__global__ __launch_bounds__(1024) void scanA_kernel(
    const int* __restrict__ cnt, int* __restrict__ off, int* __restrict__ bsum, int n)
{
    __shared__ int ssum[1024];
    const int t = threadIdx.x;
    const int g = blockIdx.x * 1024 + t;
    const int val = (g < n) ? cnt[g] : 0;
    ssum[t] = val;
    __syncthreads();
    for (int d = 1; d < 1024; d <<= 1) {
        int v = (t >= d) ? ssum[t - d] : 0;
        __syncthreads();
        ssum[t] += v;
        __syncthreads();
    }
    if (g < n) off[g] = ssum[t] - val;       // local exclusive
    if (t == 1023) bsum[blockIdx.x] = ssum[1023];
}

__global__ __launch_bounds__(512) void scanB_kernel(
    int* __restrict__ bsum, int* __restrict__ off, int nb, int n)
{
    __shared__ int ssum[512];
    const int t = threadIdx.x;
    const int val = (t < nb) ? bsum[t] : 0;
    ssum[t] = val;
    __syncthreads();
    for (int d = 1; d < 512; d <<= 1) {
        int v = (t >= d) ? ssum[t - d] : 0;
        __syncthreads();
        ssum[t] += v;
        __syncthreads();
    }
    if (t < nb) bsum[t] = ssum[t] - val;     // exclusive block offsets
    if (t == 511) off[n] = ssum[511];        // grand total
}

__global__ __launch_bounds__(1024) void scanC_kernel(
    int* __restrict__ off, int* __restrict__ woff,
    const int* __restrict__ bsum, int n)
{
    const int g = blockIdx.x * 1024 + threadIdx.x;
    if (g < n) {
        const int v = off[g] + bsum[blockIdx.x];
        off[g] = v;
        woff[g] = v;
    }
}

// bin edges: block b owns chunk b (4096 edges), label x = b&7.
// Records (src only, 4B) land in the XCD-local region [x*n_p ...].
__global__ __launch_bounds__(256) void bin_kernel(
    const int* __restrict__ src, const int* __restrict__ dst,
    int* __restrict__ woff, int* __restrict__ sorted_src, int n_edges, int n_p)
{
    const int b = blockIdx.x;
    const int x = b & (NXCD - 1);
    const int i0 = b << CHUNK_LOG2;
    const int i1 = min(i0 + (1 << CHUNK_LOG2), n_edges);
    int* wbase = woff + x * n_p;
    for (int i = i0 + threadIdx.x; i < i1; i += 256) {
        const int pos = atomicAdd(wbase + dst[i], 1);
        sorted_src[pos] = src[i];
    }
}

// one wave per pnode: softmax + weighted z-sum over 8 label-major sub-ranges
__global__ __launch_bounds__(256) void segment_kernel(
    const int* __restrict__ off, const int* __restrict__ ssrc,
    const float* __restrict__ s, const unsigned short* __restrict__ z,
    float* __restrict__ out, int n_pnodes)
{
    const int p = blockIdx.x * 4 + (threadIdx.x >> 6);
    if (p >= n_pnodes) return;
    const int lane = threadIdx.x & 63;

    int starts[8], cnts[8];
    #pragma unroll
    for (int x = 0; x < 8; ++x) {
        const int b0 = off[x * n_pnodes + p];
        const int b1 = off[x * n_pnodes + p + 1];
        starts[x] = b0;
        cnts[x] = b1 - b0;
    }
    int cum[9];
    cum[0] = 0;
    #pragma unroll
    for (int x = 0; x < 8; ++x) cum[x + 1] = cum[x] + cnts[x];
    const int len = cum[8];

    if (len == 0) {
        out[(size_t)p * OUT_DIM + lane] = 0.0f;
        return;
    }

    // lidx in [0,len) -> global record index (unrolled select chain, no scratch)
    #define MAP_J(lidx, j) do {                                        \
        j = starts[0] + (lidx);                                        \
        _Pragma("unroll")                                              \
        for (int q = 1; q < 8; ++q)                                    \
            j = ((lidx) >= cum[q]) ? (starts[q] + ((lidx) - cum[q])) : j; \
    } while (0)

    float acc = 0.0f, dsum = 0.0f;

    if (len <= 64) {
        const bool v = lane < len;
        int j; MAP_J(v ? lane : 0, j);
        const int sr = ssrc[j];
        const float e = v ? edge_score(s[sr]) : -INFINITY;
        float m = e;
        #pragma unroll
        for (int o = 32; o > 0; o >>= 1) m = fmaxf(m, __shfl_xor(m, o));
        float w = v ? __expf(e - m) : 0.0f;
        dsum = w;
        #pragma unroll
        for (int o = 32; o > 0; o >>= 1) dsum += __shfl_xor(dsum, o);

        int t = 0;
        for (; t + 4 <= len; t += 4) {
            float w0 = __shfl(w, t),     w1 = __shfl(w, t + 1);
            float w2 = __shfl(w, t + 2), w3 = __shfl(w, t + 3);
            int   s0 = __shfl(sr, t),     s1 = __shfl(sr, t + 1);
            int   s2 = __shfl(sr, t + 2), s3 = __shfl(sr, t + 3);
            float z0 = bf2f(z[(size_t)s0 * OUT_DIM + lane]);
            float z1 = bf2f(z[(size_t)s1 * OUT_DIM + lane]);
            float z2 = bf2f(z[(size_t)s2 * OUT_DIM + lane]);
            float z3 = bf2f(z[(size_t)s3 * OUT_DIM + lane]);
            acc = fmaf(w0, z0, acc); acc = fmaf(w1, z1, acc);
            acc = fmaf(w2, z2, acc); acc = fmaf(w3, z3, acc);
        }
        for (; t < len; ++t) {
            float wt = __shfl(w, t);
            int st = __shfl(sr, t);
            acc = fmaf(wt, bf2f(z[(size_t)st * OUT_DIM + lane]), acc);
        }
    } else {
        float m = -INFINITY;
        for (int c = 0; c < len; c += 64) {
            const int lidx = c + lane;
            if (lidx < len) {
                int j; MAP_J(lidx, j);
                m = fmaxf(m, edge_score(s[ssrc[j]]));
            }
        }
        #pragma unroll
        for (int o = 32; o > 0; o >>= 1) m = fmaxf(m, __shfl_xor(m, o));

        for (int c = 0; c < len; c += 64) {
            const int lidx = c + lane;
            float w = 0.0f;
            int sr = 0;
            if (lidx < len) {
                int j; MAP_J(lidx, j);
                sr = ssrc[j];
                w = __expf(edge_score(s[sr]) - m);
            }
            dsum += w;
            const int cn = min(64, len - c);
            int t = 0;
            for (; t + 4 <= cn; t += 4) {
                float w0 = __shfl(w, t),     w1 = __shfl(w, t + 1);
                float w2 = __shfl(w, t + 2), w3 = __shfl(w, t + 3);
                int   s0 = __shfl(sr, t),     s1 = __shfl(sr, t + 1);
                int   s2 = __shfl(sr, t + 2), s3 = __shfl(sr, t + 3);
                float z0 = bf2f(z[(size_t)s0 * OUT_DIM + lane]);
                float z1 = bf2f(z[(size_t)s1 * OUT_DIM + lane]);
                float z2 = bf2f(z[(size_t)s2 * OUT_DIM + lane]);
                float z3 = bf2f(z[(size_t)s3 * OUT_DIM + lane]);
                acc = fmaf(w0, z0, acc); acc = fmaf(w1, z1, acc);
                acc = fmaf(w2, z2, acc); acc = fmaf(w3, z3, acc);
            }
            for (; t < cn; ++t) {
                float wt = __shfl(w, t);
                int st = __shfl(sr, t);
                acc = fmaf(wt, bf2f(z[(size_t)st * OUT_DIM + lane]), acc);
            }
        }
        #pragma unroll
        for (int o = 32; o > 0; o >>= 1) dsum += __shfl_xor(dsum, o);
    }
    #undef MAP_J

    out[(size_t)p * OUT_DIM + lane] = acc / fmaxf(dsum, 1e-20f);
}

extern "C" void kernel_launch(void* const* d_in, const int* in_sizes, int n_in,
                              void* d_out, int out_size, void* d_ws, size_t ws_size,
                              hipStream_t stream)
{
    const float* h     = (const float*)d_in[0];
    const int*   esrc  = (const int*)d_in[1];
    const int*   edst  = (const int*)d_in[2];
    const float* Wfc   = (const float*)d_in[4];
    const float* Wattn = (const float*)d_in[5];
    float* out = (float*)d_out;

    const int n_w = in_sizes[0] / IN_DIM;   // 100000
    const int n_e = in_sizes[1];            // 1600000
    const int n_p = out_size / OUT_DIM;     // 50000
    const int N8  = n_p * NXCD;             // 400000 sub-bins (label-major)

    // workspace layout (wtf first: 16B aligned)
    short8v* wtf            = (short8v*)d_ws;                          // 2048 frags (32 KB)
    unsigned short* z       = (unsigned short*)(wtf + 2048);           // n_w*64 bf16 bits
    float* s                = (float*)(z + (size_t)n_w * OUT_DIM);     // n_w
    int* sorted_src         = (int*)(s + n_w);                         // n_e (4B each)
    int* cnt                = sorted_src + n_e;                        // N8
    int* off                = cnt + N8;                                // N8 + 1
    int* woff               = off + N8 + 1;                            // N8
    int* bsum               = woff + N8;                               // <=512

    hipMemsetAsync(cnt, 0, (size_t)N8 * sizeof(int), stream);

    prep_kernel<<<1, 256, 0, stream>>>(Wfc, wtf);
    const int gemm_blocks = (n_w + 63) / 64;
    gemm_s_kernel<<<gemm_blocks, 256, 0, stream>>>(h, wtf, Wattn, edst, z, s, cnt, n_w, n_e, n_p);

    const int nbA = (N8 + 1023) / 1024;     // 391 <= 512
    scanA_kernel<<<nbA, 1024, 0, stream>>>(cnt, off, bsum, N8);
    scanB_kernel<<<1, 512, 0, stream>>>(bsum, off, nbA, N8);
    scanC_kernel<<<nbA, 1024, 0, stream>>>(off, woff, bsum, N8);

    const int nbBin = (n_e + (1 << CHUNK_LOG2) - 1) >> CHUNK_LOG2;
    bin_kernel<<<nbBin, 256, 0, stream>>>(esrc, edst, woff, sorted_src, n_e, n_p);
    segment_kernel<<<(n_p + 3) / 4, 256, 0, stream>>>(off, sorted_src, s, z, out, n_p);
}

// Round 9
// 136.472 us; speedup vs baseline: 5.9860x; 1.5981x over previous
//
#include <hip/hip_runtime.h>
#include <hip/hip_bf16.h>
#include <math.h>

#define IN_DIM 256
#define OUT_DIM 64
#define CHUNK_LOG2 12          // 4096 edges per chunk
#define BK_LOG2 7              // 128 dsts per coarse bucket
#define MAXNB 512              // max coarse buckets supported (n_p <= 65536)

typedef __attribute__((ext_vector_type(8))) short short8v;   // 8 bf16 (4 VGPRs)
typedef __attribute__((ext_vector_type(4))) float f32x4;     // MFMA acc

__device__ __forceinline__ unsigned short f2bf(float f) {
    unsigned u = __float_as_uint(f);
    unsigned r = (u + 0x7fffu + ((u >> 16) & 1u)) >> 16;     // RTNE
    return (unsigned short)r;
}

__device__ __forceinline__ float bf2f(unsigned short b) {
    return __uint_as_float(((unsigned)b) << 16);
}

__device__ __forceinline__ float edge_score(float x) {
    float e = x > 0.0f ? x : 0.01f * x;   // leaky_relu, slope 0.01
    if (e == 0.0f) e = -1000.0f;          // where(e==0, -1000, e)
    return e;
}

// Pre-pack W_fc (256x64 f32) into MFMA B-fragments, bf16.
__global__ __launch_bounds__(256) void prep_kernel(
    const float* __restrict__ Wfc, short8v* __restrict__ wtf)
{
    const int v0 = threadIdx.x;
    for (int it = 0; it < 8; ++it) {
        const int v = v0 + it * 256;          // 0..2047
        const int ks = v >> 8;
        const int t = (v >> 6) & 3;
        const int lane = v & 63;
        const int lg = lane >> 4, lr = lane & 15;
        short8v b;
        #pragma unroll
        for (int j = 0; j < 8; ++j) {
            const int k = ks * 32 + lg * 8 + j;
            b[j] = (short)f2bf(Wfc[k * OUT_DIM + t * 16 + lr]);
        }
        wtf[v] = b;
    }
}

// z = h @ W_fc via MFMA (B in regs, no LDS staging), s = dot(z_row, W_attn[:64]).
// Fused: coarse-bucket histogram, LDS-staged (1 global atomic per chunk-bucket).
__global__ __launch_bounds__(256) void gemm_s_kernel(
    const float* __restrict__ h, const short8v* __restrict__ wtf,
    const float* __restrict__ Wattn, const int* __restrict__ edst,
    unsigned short* __restrict__ z, float* __restrict__ s,
    int* __restrict__ bcnt, int n_rows, int n_edges, int nb)
{
    __shared__ int lhist[MAXNB];
    const int tid = threadIdx.x;
    const int lane = tid & 63;
    const int wv = tid >> 6;
    const int lg = lane >> 4;
    const int lr = lane & 15;

    short8v Bf[8][4];
    #pragma unroll
    for (int ks = 0; ks < 8; ++ks)
        #pragma unroll
        for (int t = 0; t < 4; ++t)
            Bf[ks][t] = wtf[(ks * 4 + t) * 64 + lane];

    float a_attn[4];
    #pragma unroll
    for (int t = 0; t < 4; ++t) a_attn[t] = Wattn[t * 16 + lr];

    const int row0 = blockIdx.x * 64 + wv * 16;
    const float* hrow = h + (size_t)min(row0 + lr, n_rows - 1) * IN_DIM;

    float4 xv[16];
    #pragma unroll
    for (int ks = 0; ks < 8; ++ks) {
        xv[2 * ks]     = *(const float4*)(hrow + ks * 32 + lg * 8);
        xv[2 * ks + 1] = *(const float4*)(hrow + ks * 32 + lg * 8 + 4);
    }

    f32x4 acc[4];
    #pragma unroll
    for (int t = 0; t < 4; ++t) acc[t] = (f32x4){0.f, 0.f, 0.f, 0.f};

    union AB { short8v v; __hip_bfloat162 h2[4]; };
    #pragma unroll
    for (int ks = 0; ks < 8; ++ks) {
        const float4 x0 = xv[2 * ks];
        const float4 x1 = xv[2 * ks + 1];
        AB u;
        u.h2[0] = __float22bfloat162_rn(float2{x0.x, x0.y});
        u.h2[1] = __float22bfloat162_rn(float2{x0.z, x0.w});
        u.h2[2] = __float22bfloat162_rn(float2{x1.x, x1.y});
        u.h2[3] = __float22bfloat162_rn(float2{x1.z, x1.w});
        #pragma unroll
        for (int t = 0; t < 4; ++t)
            acc[t] = __builtin_amdgcn_mfma_f32_16x16x32_bf16(u.v, Bf[ks][t], acc[t], 0, 0, 0);
    }

    #pragma unroll
    for (int j = 0; j < 4; ++j) {
        const int row = row0 + lg * 4 + j;
        const bool ok = row < n_rows;
        float sv = 0.0f;
        #pragma unroll
        for (int t = 0; t < 4; ++t) {
            const float v = acc[t][j];
            if (ok) z[(size_t)row * OUT_DIM + t * 16 + lr] =
                __bfloat16_as_ushort(__float2bfloat16(v));
            sv = fmaf(v, a_attn[t], sv);
        }
        #pragma unroll
        for (int o = 1; o < 16; o <<= 1) sv += __shfl_xor(sv, o);
        if (ok && lr == 0) s[row] = sv;
    }

    // fused LDS-staged coarse-bucket histogram
    const int nchunks = (n_edges + (1 << CHUNK_LOG2) - 1) >> CHUNK_LOG2;
    for (int c = blockIdx.x; c < nchunks; c += gridDim.x) {
        for (int j = tid; j < nb; j += 256) lhist[j] = 0;
        __syncthreads();
        const int i0 = c << CHUNK_LOG2;
        const int i1 = min(i0 + (1 << CHUNK_LOG2), n_edges);
        for (int i = i0 + tid; i < i1; i += 256)
            atomicAdd(&lhist[edst[i] >> BK_LOG2], 1);
        __syncthreads();
        for (int j = tid; j < nb; j += 256) {
            const int cv = lhist[j];
            if (cv) atomicAdd(bcnt + j, cv);
        }
        __syncthreads();
    }
}

// exclusive scan of nb bucket counts -> bbase[0..nb], zero bres
__global__ __launch_bounds__(MAXNB) void bscan_kernel(
    const int* __restrict__ bcnt, int* __restrict__ bbase,
    int* __restrict__ bres, int nb)
{
    __shared__ int ssum[MAXNB];
    const int t = threadIdx.x;
    const int val = (t < nb) ? bcnt[t] : 0;
    ssum[t] = val;
    __syncthreads();
    for (int d = 1; d < MAXNB; d <<= 1) {
        int v = (t >= d) ? ssum[t - d] : 0;
        __syncthreads();
        ssum[t] += v;
        __syncthreads();
    }
    if (t < nb) {
        bbase[t] = ssum[t] - val;
        bres[t] = 0;
        if (t == nb - 1) bbase[nb] = ssum[t];
    }
}

// partition edges into coarse-bucket regions; packed record = src | (dst&127)<<17
__global__ __launch_bounds__(256) void p1_scatter_kernel(
    const int* __restrict__ src, const int* __restrict__ dst,
    const int* __restrict__ bbase, int* __restrict__ bres,
    int* __restrict__ brec, int n_edges, int nb)
{
    __shared__ int lcnt[MAXNB];
    __shared__ int lwoff[MAXNB];
    const int tid = threadIdx.x;
    const int i0 = blockIdx.x << CHUNK_LOG2;
    const int i1 = min(i0 + (1 << CHUNK_LOG2), n_edges);

    for (int j = tid; j < nb; j += 256) lcnt[j] = 0;
    __syncthreads();
    for (int i = i0 + tid; i < i1; i += 256)
        atomicAdd(&lcnt[dst[i] >> BK_LOG2], 1);
    __syncthreads();
    for (int j = tid; j < nb; j += 256) {
        const int cv = lcnt[j];
        lwoff[j] = (cv > 0) ? (bbase[j] + atomicAdd(bres + j, cv)) : 0;
    }
    __syncthreads();
    for (int i = i0 + tid; i < i1; i += 256) {
        const int d = dst[i];
        const int pos = atomicAdd(&lwoff[d >> BK_LOG2], 1);
        brec[pos] = src[i] | ((d & ((1 << BK_LOG2) - 1)) << 17);
    }
}

// per-bucket fine sort: LDS 128-bin histogram + scan; writes off[] and sorted_src.
__global__ __launch_bounds__(256) void p2_kernel(
    const int* __restrict__ bbase, const int* __restrict__ brec,
    int* __restrict__ off, int* __restrict__ sorted_src,
    int n_pnodes, int n_edges, int nb)
{
    __shared__ int lh[128];
    __shared__ int lsc[128];
    __shared__ int lwoff[128];
    const int b = blockIdx.x;
    const int tid = threadIdx.x;
    const int base = bbase[b];
    const int endb = bbase[b + 1];

    if (tid < 128) lh[tid] = 0;
    __syncthreads();
    for (int i = base + tid; i < endb; i += 256)
        atomicAdd(&lh[brec[i] >> 17], 1);
    __syncthreads();
    if (tid < 128) lsc[tid] = lh[tid];
    __syncthreads();
    for (int d = 1; d < 128; d <<= 1) {
        int v = 0;
        if (tid < 128 && tid >= d) v = lsc[tid - d];
        __syncthreads();
        if (tid < 128) lsc[tid] += v;
        __syncthreads();
    }
    const int d0 = b << BK_LOG2;
    if (tid < 128) {
        const int start = base + lsc[tid] - lh[tid];   // exclusive
        if (d0 + tid < n_pnodes) off[d0 + tid] = start;
        lwoff[tid] = start;
        if (b == nb - 1 && tid == 0) off[n_pnodes] = n_edges;
    }
    __syncthreads();
    for (int i = base + tid; i < endb; i += 256) {
        const int r = brec[i];
        const int pos = atomicAdd(&lwoff[r >> 17], 1);
        sorted_src[pos] = r & 0x1FFFF;
    }
}

// one wave per pnode: softmax + weighted z-sum over contiguous segment
__global__ __launch_bounds__(256) void segment_kernel(
    const int* __restrict__ off, const int* __restrict__ ssrc,
    const float* __restrict__ s, const unsigned short* __restrict__ z,
    float* __restrict__ out, int n_pnodes)
{
    const int p = blockIdx.x * 4 + (threadIdx.x >> 6);
    if (p >= n_pnodes) return;
    const int lane = threadIdx.x & 63;
    const int beg = off[p];
    const int end = off[p + 1];
    const int len = end - beg;

    if (len == 0) {
        out[(size_t)p * OUT_DIM + lane] = 0.0f;
        return;
    }

    float acc = 0.0f, dsum = 0.0f;

    if (len <= 64) {
        const bool v = lane < len;
        const int j = beg + (v ? lane : 0);
        const int sr = ssrc[j];
        const float e = v ? edge_score(s[sr]) : -INFINITY;
        float m = e;
        #pragma unroll
        for (int o = 32; o > 0; o >>= 1) m = fmaxf(m, __shfl_xor(m, o));
        float w = v ? __expf(e - m) : 0.0f;
        dsum = w;
        #pragma unroll
        for (int o = 32; o > 0; o >>= 1) dsum += __shfl_xor(dsum, o);

        int t = 0;
        for (; t + 4 <= len; t += 4) {
            float w0 = __shfl(w, t),     w1 = __shfl(w, t + 1);
            float w2 = __shfl(w, t + 2), w3 = __shfl(w, t + 3);
            int   s0 = __shfl(sr, t),     s1 = __shfl(sr, t + 1);
            int   s2 = __shfl(sr, t + 2), s3 = __shfl(sr, t + 3);
            float z0 = bf2f(z[(size_t)s0 * OUT_DIM + lane]);
            float z1 = bf2f(z[(size_t)s1 * OUT_DIM + lane]);
            float z2 = bf2f(z[(size_t)s2 * OUT_DIM + lane]);
            float z3 = bf2f(z[(size_t)s3 * OUT_DIM + lane]);
            acc = fmaf(w0, z0, acc); acc = fmaf(w1, z1, acc);
            acc = fmaf(w2, z2, acc); acc = fmaf(w3, z3, acc);
        }
        for (; t < len; ++t) {
            float wt = __shfl(w, t);
            int st = __shfl(sr, t);
            acc = fmaf(wt, bf2f(z[(size_t)st * OUT_DIM + lane]), acc);
        }
    } else {
        float m = -INFINITY;
        for (int j = beg + lane; j < end; j += 64)
            m = fmaxf(m, edge_score(s[ssrc[j]]));
        #pragma unroll
        for (int o = 32; o > 0; o >>= 1) m = fmaxf(m, __shfl_xor(m, o));

        for (int c = beg; c < end; c += 64) {
            const int j = c + lane;
            float w = 0.0f;
            int sr = 0;
            if (j < end) {
                sr = ssrc[j];
                w = __expf(edge_score(s[sr]) - m);
            }
            dsum += w;
            const int cn = min(64, end - c);
            int t = 0;
            for (; t + 4 <= cn; t += 4) {
                float w0 = __shfl(w, t),     w1 = __shfl(w, t + 1);
                float w2 = __shfl(w, t + 2), w3 = __shfl(w, t + 3);
                int   s0 = __shfl(sr, t),     s1 = __shfl(sr, t + 1);
                int   s2 = __shfl(sr, t + 2), s3 = __shfl(sr, t + 3);
                float z0 = bf2f(z[(size_t)s0 * OUT_DIM + lane]);
                float z1 = bf2f(z[(size_t)s1 * OUT_DIM + lane]);
                float z2 = bf2f(z[(size_t)s2 * OUT_DIM + lane]);
                float z3 = bf2f(z[(size_t)s3 * OUT_DIM + lane]);
                acc = fmaf(w0, z0, acc); acc = fmaf(w1, z1, acc);
                acc = fmaf(w2, z2, acc); acc = fmaf(w3, z3, acc);
            }
            for (; t < cn; ++t) {
                float wt = __shfl(w, t);
                int st = __shfl(sr, t);
                acc = fmaf(wt, bf2f(z[(size_t)st * OUT_DIM + lane]), acc);
            }
        }
        #pragma unroll
        for (int o = 32; o > 0; o >>= 1) dsum += __shfl_xor(dsum, o);
    }

    out[(size_t)p * OUT_DIM + lane] = acc / fmaxf(dsum, 1e-20f);
}

extern "C" void kernel_launch(void* const* d_in, const int* in_sizes, int n_in,
                              void* d_out, int out_size, void* d_ws, size_t ws_size,
                              hipStream_t stream)
{
    const float* h     = (const float*)d_in[0];
    const int*   esrc  = (const int*)d_in[1];
    const int*   edst  = (const int*)d_in[2];
    const float* Wfc   = (const float*)d_in[4];
    const float* Wattn = (const float*)d_in[5];
    float* out = (float*)d_out;

    const int n_w = in_sizes[0] / IN_DIM;   // 100000
    const int n_e = in_sizes[1];            // 1600000
    const int n_p = out_size / OUT_DIM;     // 50000
    const int nb  = (n_p + (1 << BK_LOG2) - 1) >> BK_LOG2;   // 391 coarse buckets

    // workspace layout (wtf first: 16B aligned)
    short8v* wtf            = (short8v*)d_ws;                          // 2048 frags (32 KB)
    unsigned short* z       = (unsigned short*)(wtf + 2048);           // n_w*64 bf16 bits
    float* s                = (float*)(z + (size_t)n_w * OUT_DIM);     // n_w
    int* brec               = (int*)(s + n_w);                         // n_e
    int* sorted_src         = brec + n_e;                              // n_e
    int* off                = sorted_src + n_e;                        // n_p + 1
    int* bcnt               = off + n_p + 1;                           // nb
    int* bbase              = bcnt + nb;                               // nb + 1
    int* bres               = bbase + nb + 1;                          // nb

    hipMemsetAsync(bcnt, 0, (size_t)nb * sizeof(int), stream);

    prep_kernel<<<1, 256, 0, stream>>>(Wfc, wtf);
    const int gemm_blocks = (n_w + 63) / 64;
    gemm_s_kernel<<<gemm_blocks, 256, 0, stream>>>(h, wtf, Wattn, edst, z, s, bcnt, n_w, n_e, nb);

    bscan_kernel<<<1, MAXNB, 0, stream>>>(bcnt, bbase, bres, nb);

    const int nchunks = (n_e + (1 << CHUNK_LOG2) - 1) >> CHUNK_LOG2;
    p1_scatter_kernel<<<nchunks, 256, 0, stream>>>(esrc, edst, bbase, bres, brec, n_e, nb);
    p2_kernel<<<nb, 256, 0, stream>>>(bbase, brec, off, sorted_src, n_p, n_e, nb);
    segment_kernel<<<(n_p + 3) / 4, 256, 0, stream>>>(off, sorted_src, s, z, out, n_p);
}

// Round 10
// 129.815 us; speedup vs baseline: 6.2929x; 1.0513x over previous
//
#include <hip/hip_runtime.h>
#include <hip/hip_bf16.h>
#include <math.h>

#define IN_DIM 256
#define OUT_DIM 64
#define CHUNK_LOG2 12          // 4096 edges per chunk
#define BK_LOG2 7              // 128 dsts per coarse bucket
#define MAXNB 512              // max coarse buckets (n_p <= 65536)
#define P2CAP 12288            // LDS record cap per bucket (48 KB)

typedef __attribute__((ext_vector_type(8))) short short8v;   // 8 bf16 (4 VGPRs)
typedef __attribute__((ext_vector_type(4))) float f32x4;     // MFMA acc

__device__ __forceinline__ unsigned short f2bf(float f) {
    unsigned u = __float_as_uint(f);
    unsigned r = (u + 0x7fffu + ((u >> 16) & 1u)) >> 16;     // RTNE
    return (unsigned short)r;
}

__device__ __forceinline__ float bf2f(unsigned short b) {
    return __uint_as_float(((unsigned)b) << 16);
}

__device__ __forceinline__ float edge_score(float x) {
    float e = x > 0.0f ? x : 0.01f * x;   // leaky_relu, slope 0.01
    if (e == 0.0f) e = -1000.0f;          // where(e==0, -1000, e)
    return e;
}

// async global->LDS DMA, 16B per lane; LDS dest must be linear-in-lane
__device__ __forceinline__ void gload_lds16(const void* g, void* l) {
    __builtin_amdgcn_global_load_lds(
        (const __attribute__((address_space(1))) unsigned int*)g,
        (__attribute__((address_space(3))) unsigned int*)l, 16, 0, 0);
}

// Pre-pack W_fc (256x64 f32) into MFMA B-fragments, bf16.
__global__ __launch_bounds__(256) void prep_kernel(
    const float* __restrict__ Wfc, short8v* __restrict__ wtf)
{
    const int v0 = threadIdx.x;
    for (int it = 0; it < 8; ++it) {
        const int v = v0 + it * 256;          // 0..2047
        const int ks = v >> 8;
        const int t = (v >> 6) & 3;
        const int lane = v & 63;
        const int lg = lane >> 4, lr = lane & 15;
        short8v b;
        #pragma unroll
        for (int j = 0; j < 8; ++j) {
            const int k = ks * 32 + lg * 8 + j;
            b[j] = (short)f2bf(Wfc[k * OUT_DIM + t * 16 + lr]);
        }
        wtf[v] = b;
    }
}

// z = h @ W_fc via MFMA. h-tile (64 rows x 1KB) staged by global_load_lds DMA
// with XOR-swizzled source (rule: linear LDS dest + inverse-swizzled source +
// swizzled read). Fused LDS-staged coarse histogram with reg-hoisted loads.
__global__ __launch_bounds__(256) void gemm_s_kernel(
    const float* __restrict__ h, const short8v* __restrict__ wtf,
    const float* __restrict__ Wattn, const int* __restrict__ edst,
    unsigned short* __restrict__ z, float* __restrict__ s,
    int* __restrict__ bcnt, int n_rows, int n_edges, int nb)
{
    __shared__ float hl[64 * IN_DIM];   // 64 KB; reused as lhist after compute
    const int tid = threadIdx.x;
    const int lane = tid & 63;
    const int wv = tid >> 6;
    const int lg = lane >> 4;
    const int lr = lane & 15;
    const int row0 = blockIdx.x * 64;

    // hoist histogram chunk loads (overlap with DMA + Bf loads)
    const int nchunks = (n_edges + (1 << CHUNK_LOG2) - 1) >> CHUNK_LOG2;
    const bool hasChunk = blockIdx.x < nchunks;
    const bool fullChunk = hasChunk &&
        ((blockIdx.x << CHUNK_LOG2) + (1 << CHUNK_LOG2) <= n_edges);
    int4 ed[4];
    if (fullChunk) {
        const int4* ep = (const int4*)edst + (blockIdx.x << (CHUNK_LOG2 - 2));
        #pragma unroll
        for (int j = 0; j < 4; ++j) ed[j] = ep[j * 256 + tid];
    }

    // B fragments (reg/AGPR)
    short8v Bf[8][4];
    #pragma unroll
    for (int ks = 0; ks < 8; ++ks)
        #pragma unroll
        for (int t = 0; t < 4; ++t)
            Bf[ks][t] = wtf[(ks * 4 + t) * 64 + lane];

    float a_attn[4];
    #pragma unroll
    for (int t = 0; t < 4; ++t) a_attn[t] = Wattn[t * 16 + lr];

    // stage h tile: 16 DMA issues per wave; source pre-swizzled
    #pragma unroll
    for (int i = 0; i < 16; ++i) {
        const int q = i * 256 + tid;        // 16B-slot index in tile (0..4095)
        const int row = q >> 6;             // tile row 0..63
        const int within = q & 63;          // 16B slot within row
        const int lslot = within ^ (row & 7);
        const int grow = min(row0 + row, n_rows - 1);
        gload_lds16(h + (size_t)grow * IN_DIM + lslot * 4, hl + q * 4);
    }
    __syncthreads();

    // compute: wave wv owns rows row0 + wv*16 .. +15
    f32x4 acc[4];
    #pragma unroll
    for (int t = 0; t < 4; ++t) acc[t] = (f32x4){0.f, 0.f, 0.f, 0.f};

    const int rowl = wv * 16 + lr;
    const char* rbase = (const char*)hl + rowl * 1024;
    const int swz = (lr & 7) << 4;

    union AB { short8v v; __hip_bfloat162 h2[4]; };
    #pragma unroll
    for (int ks = 0; ks < 8; ++ks) {
        const int lb = ks * 128 + lg * 32;       // logical byte offset in row
        const float4 x0 = *(const float4*)(rbase + (lb ^ swz));
        const float4 x1 = *(const float4*)(rbase + ((lb + 16) ^ swz));
        AB u;
        u.h2[0] = __float22bfloat162_rn(float2{x0.x, x0.y});
        u.h2[1] = __float22bfloat162_rn(float2{x0.z, x0.w});
        u.h2[2] = __float22bfloat162_rn(float2{x1.x, x1.y});
        u.h2[3] = __float22bfloat162_rn(float2{x1.z, x1.w});
        #pragma unroll
        for (int t = 0; t < 4; ++t)
            acc[t] = __builtin_amdgcn_mfma_f32_16x16x32_bf16(u.v, Bf[ks][t], acc[t], 0, 0, 0);
    }

    // epilogue: C/D layout col = lane&15, row = wv*16 + lg*4 + j
    #pragma unroll
    for (int j = 0; j < 4; ++j) {
        const int row = row0 + wv * 16 + lg * 4 + j;
        const bool ok = row < n_rows;
        float sv = 0.0f;
        #pragma unroll
        for (int t = 0; t < 4; ++t) {
            const float v = acc[t][j];
            if (ok) z[(size_t)row * OUT_DIM + t * 16 + lr] =
                __bfloat16_as_ushort(__float2bfloat16(v));
            sv = fmaf(v, a_attn[t], sv);
        }
        #pragma unroll
        for (int o = 1; o < 16; o <<= 1) sv += __shfl_xor(sv, o);
        if (ok && lr == 0) s[row] = sv;
    }

    // fused histogram (reuse hl as lhist)
    __syncthreads();
    int* lhist = (int*)hl;
    for (int j2 = tid; j2 < nb; j2 += 256) lhist[j2] = 0;
    __syncthreads();
    if (fullChunk) {
        #pragma unroll
        for (int j2 = 0; j2 < 4; ++j2) {
            atomicAdd(&lhist[ed[j2].x >> BK_LOG2], 1);
            atomicAdd(&lhist[ed[j2].y >> BK_LOG2], 1);
            atomicAdd(&lhist[ed[j2].z >> BK_LOG2], 1);
            atomicAdd(&lhist[ed[j2].w >> BK_LOG2], 1);
        }
    } else if (hasChunk) {
        const int i0 = blockIdx.x << CHUNK_LOG2;
        const int i1 = min(i0 + (1 << CHUNK_LOG2), n_edges);
        for (int i = i0 + tid; i < i1; i += 256)
            atomicAdd(&lhist[edst[i] >> BK_LOG2], 1);
    }
    __syncthreads();
    if (hasChunk)
        for (int j2 = tid; j2 < nb; j2 += 256) {
            const int cv = lhist[j2];
            if (cv) atomicAdd(bcnt + j2, cv);
        }
}

// exclusive scan of nb bucket counts -> bbase[0..nb], zero bres
__global__ __launch_bounds__(MAXNB) void bscan_kernel(
    const int* __restrict__ bcnt, int* __restrict__ bbase,
    int* __restrict__ bres, int nb)
{
    __shared__ int ssum[MAXNB];
    const int t = threadIdx.x;
    const int val = (t < nb) ? bcnt[t] : 0;
    ssum[t] = val;
    __syncthreads();
    for (int d = 1; d < MAXNB; d <<= 1) {
        int v = (t >= d) ? ssum[t - d] : 0;
        __syncthreads();
        ssum[t] += v;
        __syncthreads();
    }
    if (t < nb) {
        bbase[t] = ssum[t] - val;
        bres[t] = 0;
        if (t == nb - 1) bbase[nb] = ssum[t];
    }
}

// partition edges into coarse-bucket regions; packed record = src | (dst&127)<<17
__global__ __launch_bounds__(256) void p1_scatter_kernel(
    const int* __restrict__ src, const int* __restrict__ dst,
    const int* __restrict__ bbase, int* __restrict__ bres,
    int* __restrict__ brec, int n_edges, int nb)
{
    __shared__ int lcnt[MAXNB];
    __shared__ int lwoff[MAXNB];
    const int tid = threadIdx.x;
    const int i0 = blockIdx.x << CHUNK_LOG2;
    const int i1 = min(i0 + (1 << CHUNK_LOG2), n_edges);
    const bool full = (i1 - i0) == (1 << CHUNK_LOG2);

    int4 s4[4], d4[4];
    if (full) {
        const int4* sp = (const int4*)src + (i0 >> 2);
        const int4* dp = (const int4*)dst + (i0 >> 2);
        #pragma unroll
        for (int j = 0; j < 4; ++j) {
            s4[j] = sp[j * 256 + tid];
            d4[j] = dp[j * 256 + tid];
        }
    }

    for (int j = tid; j < nb; j += 256) lcnt[j] = 0;
    __syncthreads();
    if (full) {
        #pragma unroll
        for (int j = 0; j < 4; ++j) {
            atomicAdd(&lcnt[d4[j].x >> BK_LOG2], 1);
            atomicAdd(&lcnt[d4[j].y >> BK_LOG2], 1);
            atomicAdd(&lcnt[d4[j].z >> BK_LOG2], 1);
            atomicAdd(&lcnt[d4[j].w >> BK_LOG2], 1);
        }
    } else {
        for (int i = i0 + tid; i < i1; i += 256)
            atomicAdd(&lcnt[dst[i] >> BK_LOG2], 1);
    }
    __syncthreads();
    for (int j = tid; j < nb; j += 256) {
        const int cv = lcnt[j];
        lwoff[j] = (cv > 0) ? (bbase[j] + atomicAdd(bres + j, cv)) : 0;
    }
    __syncthreads();
    if (full) {
        #pragma unroll
        for (int j = 0; j < 4; ++j) {
            #define P1EMIT(dd, ss) { \
                const int pos = atomicAdd(&lwoff[(dd) >> BK_LOG2], 1); \
                brec[pos] = (ss) | (((dd) & ((1 << BK_LOG2) - 1)) << 17); }
            P1EMIT(d4[j].x, s4[j].x)
            P1EMIT(d4[j].y, s4[j].y)
            P1EMIT(d4[j].z, s4[j].z)
            P1EMIT(d4[j].w, s4[j].w)
            #undef P1EMIT
        }
    } else {
        for (int i = i0 + tid; i < i1; i += 256) {
            const int d = dst[i];
            const int pos = atomicAdd(&lwoff[d >> BK_LOG2], 1);
            brec[pos] = src[i] | ((d & ((1 << BK_LOG2) - 1)) << 17);
        }
    }
}

// per-bucket fine sort: records staged in LDS; writes off[] and sorted_src.
__global__ __launch_bounds__(256) void p2_kernel(
    const int* __restrict__ bbase, const int* __restrict__ brec,
    int* __restrict__ off, int* __restrict__ sorted_src,
    int n_pnodes, int n_edges, int nb)
{
    __shared__ int srec[P2CAP];
    __shared__ int lh[128];
    __shared__ int lsc[128];
    __shared__ int lwoff[128];
    const int b = blockIdx.x;
    const int tid = threadIdx.x;
    const int base = bbase[b];
    const int endb = bbase[b + 1];
    const int len = endb - base;
    const bool inLds = len <= P2CAP;

    if (tid < 128) lh[tid] = 0;
    if (inLds)
        for (int i = tid; i < len; i += 256) srec[i] = brec[base + i];
    __syncthreads();
    if (inLds) {
        for (int i = tid; i < len; i += 256)
            atomicAdd(&lh[srec[i] >> 17], 1);
    } else {
        for (int i = base + tid; i < endb; i += 256)
            atomicAdd(&lh[brec[i] >> 17], 1);
    }
    __syncthreads();
    if (tid < 128) lsc[tid] = lh[tid];
    __syncthreads();
    for (int d = 1; d < 128; d <<= 1) {
        int v = 0;
        if (tid < 128 && tid >= d) v = lsc[tid - d];
        __syncthreads();
        if (tid < 128) lsc[tid] += v;
        __syncthreads();
    }
    const int d0 = b << BK_LOG2;
    if (tid < 128) {
        const int start = base + lsc[tid] - lh[tid];   // exclusive
        if (d0 + tid < n_pnodes) off[d0 + tid] = start;
        lwoff[tid] = start;
        if (b == nb - 1 && tid == 0) off[n_pnodes] = n_edges;
    }
    __syncthreads();
    if (inLds) {
        for (int i = tid; i < len; i += 256) {
            const int r = srec[i];
            const int pos = atomicAdd(&lwoff[r >> 17], 1);
            sorted_src[pos] = r & 0x1FFFF;
        }
    } else {
        for (int i = base + tid; i < endb; i += 256) {
            const int r = brec[i];
            const int pos = atomicAdd(&lwoff[r >> 17], 1);
            sorted_src[pos] = r & 0x1FFFF;
        }
    }
}

// one wave per pnode: softmax + weighted z-sum over contiguous segment
__global__ __launch_bounds__(256) void segment_kernel(
    const int* __restrict__ off, const int* __restrict__ ssrc,
    const float* __restrict__ s, const unsigned short* __restrict__ z,
    float* __restrict__ out, int n_pnodes)
{
    const int p = blockIdx.x * 4 + (threadIdx.x >> 6);
    if (p >= n_pnodes) return;
    const int lane = threadIdx.x & 63;
    const int beg = off[p];
    const int end = off[p + 1];
    const int len = end - beg;

    if (len == 0) {
        out[(size_t)p * OUT_DIM + lane] = 0.0f;
        return;
    }

    float acc = 0.0f, dsum = 0.0f;

    #define GATH1(tt, wsrc, ssrcv) { \
        float wt = __shfl(wsrc, tt); \
        int st = __shfl(ssrcv, tt); \
        acc = fmaf(wt, bf2f(z[(size_t)st * OUT_DIM + lane]), acc); }
    #define GATH8(tt, wsrc, ssrcv) { \
        float w0 = __shfl(wsrc, tt),     w1 = __shfl(wsrc, tt + 1); \
        float w2 = __shfl(wsrc, tt + 2), w3 = __shfl(wsrc, tt + 3); \
        float w4 = __shfl(wsrc, tt + 4), w5 = __shfl(wsrc, tt + 5); \
        float w6 = __shfl(wsrc, tt + 6), w7 = __shfl(wsrc, tt + 7); \
        int a0 = __shfl(ssrcv, tt),     a1 = __shfl(ssrcv, tt + 1); \
        int a2 = __shfl(ssrcv, tt + 2), a3 = __shfl(ssrcv, tt + 3); \
        int a4 = __shfl(ssrcv, tt + 4), a5 = __shfl(ssrcv, tt + 5); \
        int a6 = __shfl(ssrcv, tt + 6), a7 = __shfl(ssrcv, tt + 7); \
        float z0 = bf2f(z[(size_t)a0 * OUT_DIM + lane]); \
        float z1 = bf2f(z[(size_t)a1 * OUT_DIM + lane]); \
        float z2 = bf2f(z[(size_t)a2 * OUT_DIM + lane]); \
        float z3 = bf2f(z[(size_t)a3 * OUT_DIM + lane]); \
        float z4 = bf2f(z[(size_t)a4 * OUT_DIM + lane]); \
        float z5 = bf2f(z[(size_t)a5 * OUT_DIM + lane]); \
        float z6 = bf2f(z[(size_t)a6 * OUT_DIM + lane]); \
        float z7 = bf2f(z[(size_t)a7 * OUT_DIM + lane]); \
        acc = fmaf(w0, z0, acc); acc = fmaf(w1, z1, acc); \
        acc = fmaf(w2, z2, acc); acc = fmaf(w3, z3, acc); \
        acc = fmaf(w4, z4, acc); acc = fmaf(w5, z5, acc); \
        acc = fmaf(w6, z6, acc); acc = fmaf(w7, z7, acc); }

    if (len <= 64) {
        const bool v = lane < len;
        const int j = beg + (v ? lane : 0);
        const int sr = ssrc[j];
        const float e = v ? edge_score(s[sr]) : -INFINITY;
        float m = e;
        #pragma unroll
        for (int o = 32; o > 0; o >>= 1) m = fmaxf(m, __shfl_xor(m, o));
        float w = v ? __expf(e - m) : 0.0f;
        dsum = w;
        #pragma unroll
        for (int o = 32; o > 0; o >>= 1) dsum += __shfl_xor(dsum, o);

        int t = 0;
        for (; t + 8 <= len; t += 8) GATH8(t, w, sr)
        for (; t < len; ++t) GATH1(t, w, sr)
    } else {
        float m = -INFINITY;
        for (int j = beg + lane; j < end; j += 64)
            m = fmaxf(m, edge_score(s[ssrc[j]]));
        #pragma unroll
        for (int o = 32; o > 0; o >>= 1) m = fmaxf(m, __shfl_xor(m, o));

        for (int c = beg; c < end; c += 64) {
            const int j = c + lane;
            float w = 0.0f;
            int sr = 0;
            if (j < end) {
                sr = ssrc[j];
                w = __expf(edge_score(s[sr]) - m);
            }
            dsum += w;
            const int cn = min(64, end - c);
            int t = 0;
            for (; t + 8 <= cn; t += 8) GATH8(t, w, sr)
            for (; t < cn; ++t) GATH1(t, w, sr)
        }
        #pragma unroll
        for (int o = 32; o > 0; o >>= 1) dsum += __shfl_xor(dsum, o);
    }
    #undef GATH8
    #undef GATH1

    out[(size_t)p * OUT_DIM + lane] = acc / fmaxf(dsum, 1e-20f);
}

extern "C" void kernel_launch(void* const* d_in, const int* in_sizes, int n_in,
                              void* d_out, int out_size, void* d_ws, size_t ws_size,
                              hipStream_t stream)
{
    const float* h     = (const float*)d_in[0];
    const int*   esrc  = (const int*)d_in[1];
    const int*   edst  = (const int*)d_in[2];
    const float* Wfc   = (const float*)d_in[4];
    const float* Wattn = (const float*)d_in[5];
    float* out = (float*)d_out;

    const int n_w = in_sizes[0] / IN_DIM;   // 100000
    const int n_e = in_sizes[1];            // 1600000
    const int n_p = out_size / OUT_DIM;     // 50000
    const int nb  = (n_p + (1 << BK_LOG2) - 1) >> BK_LOG2;   // 391 coarse buckets

    // workspace layout (wtf first: 16B aligned)
    short8v* wtf            = (short8v*)d_ws;                          // 2048 frags (32 KB)
    unsigned short* z       = (unsigned short*)(wtf + 2048);           // n_w*64 bf16 bits
    float* s                = (float*)(z + (size_t)n_w * OUT_DIM);     // n_w
    int* brec               = (int*)(s + n_w);                         // n_e
    int* sorted_src         = brec + n_e;                              // n_e
    int* off                = sorted_src + n_e;                        // n_p + 1
    int* bcnt               = off + n_p + 1;                           // nb
    int* bbase              = bcnt + nb;                               // nb + 1
    int* bres               = bbase + nb + 1;                          // nb

    hipMemsetAsync(bcnt, 0, (size_t)nb * sizeof(int), stream);

    prep_kernel<<<1, 256, 0, stream>>>(Wfc, wtf);
    const int gemm_blocks = (n_w + 63) / 64;
    gemm_s_kernel<<<gemm_blocks, 256, 0, stream>>>(h, wtf, Wattn, edst, z, s, bcnt, n_w, n_e, nb);

    bscan_kernel<<<1, MAXNB, 0, stream>>>(bcnt, bbase, bres, nb);

    const int nchunks = (n_e + (1 << CHUNK_LOG2) - 1) >> CHUNK_LOG2;
    p1_scatter_kernel<<<nchunks, 256, 0, stream>>>(esrc, edst, bbase, bres, brec, n_e, nb);
    p2_kernel<<<nb, 256, 0, stream>>>(bbase, brec, off, sorted_src, n_p, n_e, nb);
    segment_kernel<<<(n_p + 3) / 4, 256, 0, stream>>>(off, sorted_src, s, z, out, n_p);
}